// Round 1
// baseline (6231.110 us; speedup 1.0000x reference)
//
#include <hip/hip_runtime.h>
#include <math.h>

#define B_ 32
#define T_ 200
#define D_ 256
#define H_ 4
#define DH_ 32
#define INNER_ 128
#define L_ 8
#define FF_ 1024
#define NI_ 100000
#define NB_ 64

__device__ __forceinline__ float gelu_f(float x){
  return 0.5f*x*(1.0f+erff(x*0.70710678118654752f));
}
__device__ __forceinline__ float wsum(float v){
  #pragma unroll
  for (int o=32;o>0;o>>=1) v += __shfl_xor(v,o,64);
  return v;
}

// ---------------- embedding + time features ----------------
__global__ __launch_bounds__(256) void k_embed(
  const int* __restrict__ ids, const int* __restrict__ ts, const int* __restrict__ lens,
  const float* __restrict__ item_emb, const float* __restrict__ pos_emb,
  const float* __restrict__ gap_emb, const float* __restrict__ rec_emb,
  const float* __restrict__ tf_w1, const float* __restrict__ tf_b1,
  float* __restrict__ xbuf, float* __restrict__ tfh)
{
  int bt = blockIdx.x;
  int b = bt / T_, t = bt % T_;
  int d = threadIdx.x;
  int len = lens[b];
  int tcur = ts[b*T_+t];
  int tlast = ts[b*T_+T_-1];
  bool mask  = t >= T_ - len;
  bool pmask = (t >= 1) && ((t-1) >= T_ - len);
  int gap = 0;
  if (mask && pmask){ int pv = ts[b*T_+t-1]; gap = max(tcur - pv, 0); }
  int rec = mask ? max(tlast - tcur, 0) : 0;
  int gb = min(max((int)floorf(log2f((float)gap + 1.0f)), 0), NB_-1);
  int rb = min(max((int)floorf(log2f((float)rec + 1.0f)), 0), NB_-1);
  float rec_raw = (float)max(tlast - tcur, 0);   // NOT masked, per reference
  float tf0 = log1pf((float)gb);
  float tf1 = log1pf(rec_raw);
  float hid = gelu_f(tf0*tf_w1[d] + tf1*tf_w1[D_+d] + tf_b1[d]);
  tfh[(size_t)bt*D_ + d] = hid;
  int id = ids[b*T_+t];
  xbuf[(size_t)bt*D_ + d] = item_emb[(size_t)id*D_ + d] + pos_emb[t*D_ + d]
                          + gap_emb[gb*D_ + d] + rec_emb[rb*D_ + d];
}

// ---------------- LayerNorm (wave per row), optional mask multiply ----------------
template<int NC>   // D = NC*256
__global__ __launch_bounds__(256) void k_ln(
  const float* __restrict__ in, float* __restrict__ out,
  const float* __restrict__ g, const float* __restrict__ bb,
  int rows, const int* __restrict__ lens, int applyMask)
{
  int wid = threadIdx.x >> 6, lane = threadIdx.x & 63;
  int r = blockIdx.x*4 + wid;
  if (r >= rows) return;
  const int D = NC*256;
  const float4* rp = (const float4*)(in + (size_t)r*D);
  float4 v[NC];
  float s = 0.f;
  #pragma unroll
  for (int c=0;c<NC;c++){ v[c] = rp[c*64 + lane]; s += v[c].x+v[c].y+v[c].z+v[c].w; }
  s = wsum(s);
  float mean = s / (float)D;
  float q = 0.f;
  #pragma unroll
  for (int c=0;c<NC;c++){
    float a=v[c].x-mean, b2=v[c].y-mean, c2=v[c].z-mean, d2=v[c].w-mean;
    q += a*a + b2*b2 + c2*c2 + d2*d2;
  }
  q = wsum(q);
  float rstd = rsqrtf(q/(float)D + 1e-5f);
  float m = 1.f;
  if (applyMask){ int t = r % T_; int b = r / T_; m = (t >= T_ - lens[b]) ? 1.f : 0.f; }
  float4* op = (float4*)(out + (size_t)r*D);
  #pragma unroll
  for (int c=0;c<NC;c++){
    float4 gg  = ((const float4*)g )[c*64+lane];
    float4 bv  = ((const float4*)bb)[c*64+lane];
    float4 o;
    o.x = ((v[c].x-mean)*rstd*gg.x + bv.x)*m;
    o.y = ((v[c].y-mean)*rstd*gg.y + bv.y)*m;
    o.z = ((v[c].z-mean)*rstd*gg.z + bv.z)*m;
    o.w = ((v[c].w-mean)*rstd*gg.w + bv.w)*m;
    op[c*64+lane] = o;
  }
}

// ---------------- generic fp32 GEMM: C[M,N] = A[M,K] @ W[K,N] (+bias)(+act) ----------------
// mode: 0 = +bias; 1 = gelu(+bias); 2 = +bias + existing C (accumulate)
__global__ __launch_bounds__(256) void k_gemm(
    const float* __restrict__ A, const float* __restrict__ W,
    const float* __restrict__ bias, float* __restrict__ C,
    int M, int N, int K, int ldA, int ldC, int mode)
{
  __shared__ float As[16][132];
  __shared__ float Ws[16][64];
  int tid = threadIdx.x;
  int bm = blockIdx.y * 128, bn = blockIdx.x * 64;
  int tx = tid & 15, ty = tid >> 4;
  float acc[8][4];
  #pragma unroll
  for (int i=0;i<8;i++)
    #pragma unroll
    for (int j=0;j<4;j++) acc[i][j]=0.f;
  for (int k0=0;k0<K;k0+=16){
    #pragma unroll
    for (int i=0;i<8;i++){
      int idx = tid + i*256;
      int m = idx >> 4, kk = idx & 15;
      float v = 0.f;
      int gm = bm + m;
      if (gm < M) v = A[(size_t)gm*ldA + k0 + kk];
      As[kk][m] = v;
    }
    #pragma unroll
    for (int i=0;i<4;i++){
      int idx = tid + i*256;
      int kk = idx >> 6, n = idx & 63;
      Ws[kk][n] = W[(size_t)(k0+kk)*N + bn + n];
    }
    __syncthreads();
    #pragma unroll
    for (int kk=0;kk<16;kk++){
      float4 a0 = *(const float4*)&As[kk][ty*8];
      float4 a1 = *(const float4*)&As[kk][ty*8+4];
      float4 w0 = *(const float4*)&Ws[kk][tx*4];
      float a[8] = {a0.x,a0.y,a0.z,a0.w,a1.x,a1.y,a1.z,a1.w};
      float w[4] = {w0.x,w0.y,w0.z,w0.w};
      #pragma unroll
      for (int i=0;i<8;i++)
        #pragma unroll
        for (int j=0;j<4;j++) acc[i][j] += a[i]*w[j];
    }
    __syncthreads();
  }
  #pragma unroll
  for (int i=0;i<8;i++){
    int m = bm + ty*8 + i;
    if (m < M){
      #pragma unroll
      for (int j=0;j<4;j++){
        int n = bn + tx*4 + j;
        float v = acc[i][j];
        if (bias) v += bias[n];
        if (mode == 1) v = gelu_f(v);
        float* cp = &C[(size_t)m*ldC + n];
        if (mode == 2) v += *cp;
        *cp = v;
      }
    }
  }
}

// ---------------- causal linear attention: one block (64 thr) per (b,h) ----------------
#define CH_ 25
__global__ __launch_bounds__(64) void k_attn(
  const float* __restrict__ proj, const int* __restrict__ lens, float* __restrict__ attn)
{
  int bh = blockIdx.x; int b = bh >> 2, h = bh & 3;
  int lane = threadIdx.x; int e = lane & 31; int half = lane >> 5;
  int tstart = T_ - lens[b];
  __shared__ float sq[CH_*32], sk[CH_*32], sv[CH_*32];
  float kv[16]; float kp[16];
  #pragma unroll
  for (int j=0;j<16;j++){ kv[j]=0.f; kp[j]=0.f; }
  for (int c=0;c<T_/CH_;c++){
    int t0 = c*CH_;
    __syncthreads();
    for (int idx=lane; idx<CH_*32; idx+=64){
      int tl = idx >> 5, dd = idx & 31;
      int t = t0 + tl;
      float m = (t >= tstart) ? 1.f : 0.f;
      const float* pr = proj + (size_t)(b*T_+t)*640 + h*32 + dd;
      float qv = pr[256], kw = pr[384], vv = pr[512];
      qv = (qv > 0.f ? qv + 1.f : __expf(qv)) * m;   // elu(q)+1, masked
      kw = (kw > 0.f ? kw + 1.f : __expf(kw)) * m;
      sq[idx] = qv; sk[idx] = kw; sv[idx] = vv * m;
    }
    __syncthreads();
    for (int tl=0; tl<CH_; tl++){
      const float4* q4 = (const float4*)(sq + tl*32 + half*16);
      const float4* k4 = (const float4*)(sk + tl*32 + half*16);
      float vf = sv[tl*32 + e];
      float num=0.f, den=0.f, qk=0.f;
      #pragma unroll
      for (int jj=0;jj<4;jj++){
        float4 qq = q4[jj]; float4 kk = k4[jj];
        int j = jj*4;
        num += qq.x*kv[j] + qq.y*kv[j+1] + qq.z*kv[j+2] + qq.w*kv[j+3];
        den += qq.x*kp[j] + qq.y*kp[j+1] + qq.z*kp[j+2] + qq.w*kp[j+3];
        qk  += qq.x*kk.x + qq.y*kk.y + qq.z*kk.z + qq.w*kk.w;
        kv[j]   += kk.x*vf; kv[j+1] += kk.y*vf; kv[j+2] += kk.z*vf; kv[j+3] += kk.w*vf;
        kp[j]   += kk.x;    kp[j+1] += kk.y;    kp[j+2] += kk.z;    kp[j+3] += kk.w;
      }
      num += __shfl_xor(num,32,64);
      den += __shfl_xor(den,32,64);
      qk  += __shfl_xor(qk ,32,64);
      int t = t0 + tl;
      float m = (t >= tstart) ? 1.f : 0.f;
      num += qk * vf;     // include current step (inclusive cumsum)
      den += qk;
      float o = num/(den + 1e-6f)*m;
      if (half == 0) attn[(size_t)(b*T_+t)*128 + h*32 + e] = o;
    }
  }
}

// ---------------- depthwise causal convs (k=3 and k=5) into cat buffer ----------------
__global__ __launch_bounds__(256) void k_dwconv(
  const float* __restrict__ nrm, const float* __restrict__ tw, const float* __restrict__ tb,
  const float* __restrict__ pw, const float* __restrict__ pb, float* __restrict__ cat)
{
  int idx = blockIdx.x*256 + threadIdx.x;
  int d = idx & 255; int bt = idx >> 8; int t = bt % T_;
  float xs[5];
  #pragma unroll
  for (int j=0;j<5;j++){
    int tt = t - 4 + j;
    xs[j] = (tt >= 0) ? nrm[(size_t)(bt - 4 + j)*D_ + d] : 0.f;
  }
  float tmp = tw[d*3+0]*xs[2] + tw[d*3+1]*xs[3] + tw[d*3+2]*xs[4] + tb[d];
  float pos = pb[d];
  #pragma unroll
  for (int j=0;j<5;j++) pos += pw[d*5+j]*xs[j];
  cat[(size_t)bt*768 + 256 + d] = tmp;
  cat[(size_t)bt*768 + 512 + d] = pos;
}

// ---------------- gated residual: x = (x + sigmoid(gate)*mixed)*mask ----------------
__global__ __launch_bounds__(256) void k_postmix(
  float* __restrict__ x, const float* __restrict__ proj, const float* __restrict__ mixed,
  const int* __restrict__ lens)
{
  int idx = blockIdx.x*256 + threadIdx.x;
  int d = idx & 255; int bt = idx >> 8; int t = bt % T_, b = bt / T_;
  float m = (t >= T_ - lens[b]) ? 1.f : 0.f;
  float g = proj[(size_t)bt*640 + d];
  float s = 1.f/(1.f + __expf(-g));
  x[idx] = (x[idx] + s*mixed[idx])*m;
}

__global__ __launch_bounds__(256) void k_addmask(
  float* __restrict__ x, const float* __restrict__ f, const int* __restrict__ lens)
{
  int idx = blockIdx.x*256 + threadIdx.x;
  int bt = idx >> 8; int t = bt % T_, b = bt / T_;
  float m = (t >= T_ - lens[b]) ? 1.f : 0.f;
  x[idx] = (x[idx] + f[idx])*m;
}

// ---------------- pooling: last / mean / softmax-attn -> u0 (B,768) ----------------
__global__ __launch_bounds__(256) void k_pool(
  const float* __restrict__ x, const int* __restrict__ lens,
  const float* __restrict__ pg_w, const float* __restrict__ pg_b,
  float* __restrict__ u0)
{
  int b = blockIdx.x;
  int tid = threadIdx.x, wid = tid>>6, lane = tid&63;
  __shared__ float sps[T_];
  __shared__ float spw[T_];
  int len = lens[b]; int tstart = T_ - len;
  const float4* pw4 = (const float4*)pg_w;
  float4 wv = pw4[lane];
  for (int t = wid; t < T_; t += 4){
    const float4* xr = (const float4*)(x + (size_t)(b*T_+t)*D_);
    float4 xv = xr[lane];
    float dot = xv.x*wv.x + xv.y*wv.y + xv.z*wv.z + xv.w*wv.w;
    dot = wsum(dot);
    if (lane==0) sps[t] = (t >= tstart) ? dot + pg_b[0] : -1e9f;
  }
  __syncthreads();
  float mx = -1e30f;
  for (int t=0;t<T_;t++) mx = fmaxf(mx, sps[t]);
  float sum = 0.f;
  for (int t=0;t<T_;t++) sum += __expf(sps[t]-mx);
  float inv = 1.f/sum;
  if (tid < T_) spw[tid] = __expf(sps[tid]-mx)*inv;
  __syncthreads();
  int d = tid;
  float macc=0.f, aacc=0.f;
  for (int t=0;t<T_;t++){
    float v = x[(size_t)(b*T_+t)*D_ + d];
    macc += v;
    aacc += spw[t]*v;
  }
  u0[b*768 + d]       = x[(size_t)(b*T_+T_-1)*D_ + d];
  u0[b*768 + 256 + d] = macc / (float)max(len,1);
  u0[b*768 + 512 + d] = aacc;
}

// ---------------- normalize u rows ----------------
__global__ __launch_bounds__(64) void k_norm(float* __restrict__ u)
{
  int b = blockIdx.x; int lane = threadIdx.x;
  float4* r = (float4*)(u + b*256);
  float4 v = r[lane];
  float ss = v.x*v.x + v.y*v.y + v.z*v.z + v.w*v.w;
  ss = wsum(ss);
  float sc = 1.f/fmaxf(sqrtf(ss), 1e-12f);
  v.x*=sc; v.y*=sc; v.z*=sc; v.w*=sc;
  r[lane]=v;
}

// ---------------- scoring: out[b, n] = u[b] . normalize(item_emb[n+1]) + bias[n+1] ----------------
__global__ __launch_bounds__(256) void k_score(
  const float* __restrict__ u, const float* __restrict__ item_emb,
  const float* __restrict__ item_bias, float* __restrict__ out)
{
  __shared__ float su[D_][B_];      // u transposed: su[k][b]
  __shared__ float Wt[16][260];     // item slice, padded
  int tid = threadIdx.x;
  for (int i = tid; i < B_*D_; i += 256){
    int b = i & 31, k = i >> 5;
    su[k][b] = u[b*D_ + k];
  }
  int n0 = blockIdx.x * 256;
  int n = n0 + tid;
  float acc[B_];
  #pragma unroll
  for (int b=0;b<B_;b++) acc[b]=0.f;
  float ss = 0.f;
  for (int k0=0; k0<D_; k0+=16){
    __syncthreads();
    for (int i = tid; i < 256*16; i += 256){
      int il = i >> 4, kk = i & 15;
      int ni = n0 + il;
      float v = 0.f;
      if (ni < NI_) v = item_emb[(size_t)(ni+1)*D_ + k0 + kk];
      Wt[kk][il] = v;
    }
    __syncthreads();
    #pragma unroll
    for (int kk=0;kk<16;kk++){
      float wv = Wt[kk][tid];
      ss += wv*wv;
      const float4* su4 = (const float4*)su[k0+kk];
      #pragma unroll
      for (int b4=0;b4<8;b4++){
        float4 uu = su4[b4];
        acc[b4*4+0] += uu.x*wv;
        acc[b4*4+1] += uu.y*wv;
        acc[b4*4+2] += uu.z*wv;
        acc[b4*4+3] += uu.w*wv;
      }
    }
  }
  if (n < NI_){
    float sc = 1.f/fmaxf(sqrtf(ss), 1e-12f);
    float bias = item_bias[n+1];
    #pragma unroll
    for (int b=0;b<B_;b++){
      out[(size_t)b*NI_ + n] = acc[b]*sc + bias;
    }
  }
}

extern "C" void kernel_launch(void* const* d_in, const int* in_sizes, int n_in,
                              void* d_out, int out_size, void* d_ws, size_t ws_size,
                              hipStream_t stream)
{
  const int* ids  = (const int*)d_in[0];
  const int* ts   = (const int*)d_in[1];
  const int* lens = (const int*)d_in[2];
  const float* item_emb = (const float*)d_in[3];
  const float* pos_emb  = (const float*)d_in[4];
  const float* gap_emb  = (const float*)d_in[5];
  const float* rec_emb  = (const float*)d_in[6];
  const float* tf_w1 = (const float*)d_in[7];
  const float* tf_b1 = (const float*)d_in[8];
  const float* tf_w2 = (const float*)d_in[9];
  const float* tf_b2 = (const float*)d_in[10];
  const float* in_g  = (const float*)d_in[11];
  const float* in_b  = (const float*)d_in[12];
  const float* l_ln1g = (const float*)d_in[13];
  const float* l_ln1b = (const float*)d_in[14];
  const float* l_win  = (const float*)d_in[15];
  const float* l_bin  = (const float*)d_in[16];
  const float* l_wc   = (const float*)d_in[17];
  const float* l_bc   = (const float*)d_in[18];
  const float* l_tw   = (const float*)d_in[19];
  const float* l_tb   = (const float*)d_in[20];
  const float* l_pw   = (const float*)d_in[21];
  const float* l_pb   = (const float*)d_in[22];
  const float* l_wmix = (const float*)d_in[23];
  const float* l_bmix = (const float*)d_in[24];
  const float* l_ln2g = (const float*)d_in[25];
  const float* l_ln2b = (const float*)d_in[26];
  const float* l_wf1  = (const float*)d_in[27];
  const float* l_bf1  = (const float*)d_in[28];
  const float* l_wf2  = (const float*)d_in[29];
  const float* l_bf2  = (const float*)d_in[30];
  const float* fn_g = (const float*)d_in[31];
  const float* fn_b = (const float*)d_in[32];
  const float* pg_w = (const float*)d_in[33];
  const float* pg_b = (const float*)d_in[34];
  const float* uh_w1 = (const float*)d_in[35];
  const float* uh_b1 = (const float*)d_in[36];
  const float* uh_lng = (const float*)d_in[37];
  const float* uh_lnb = (const float*)d_in[38];
  const float* uh_w2 = (const float*)d_in[39];
  const float* uh_b2 = (const float*)d_in[40];
  const float* item_bias = (const float*)d_in[41];
  float* out = (float*)d_out;

  const int MT = B_*T_;            // 6400 rows
  float* ws   = (float*)d_ws;
  float* xbuf = ws;                              // 1,638,400
  float* tmp  = xbuf + (size_t)MT*D_;            // 1,638,400 (nrm / mix-out / ffn2-out / tfh)
  float* proj = tmp  + (size_t)MT*D_;            // 4,096,000
  float* attn = proj + (size_t)MT*640;           //   819,200
  float* cat  = attn + (size_t)MT*128;           // 4,915,200 (also reused as h)
  float* mid  = cat  + (size_t)MT*768;           // 6,553,600
  float* u0   = mid  + (size_t)MT*FF_;           // 24,576
  float* u1   = u0 + 32*768;                     // 32,768
  float* u2   = u1 + 32*1024;                    // 8,192

  // ---- embedding + dense time ----
  k_embed<<<MT, 256, 0, stream>>>(ids, ts, lens, item_emb, pos_emb, gap_emb, rec_emb,
                                  tf_w1, tf_b1, xbuf, tmp);
  k_gemm<<<dim3(4,50), 256, 0, stream>>>(tmp, tf_w2, tf_b2, xbuf, MT, 256, 256, 256, 256, 2);
  k_ln<1><<<MT/4, 256, 0, stream>>>(xbuf, xbuf, in_g, in_b, MT, lens, 1);

  // ---- layers ----
  for (int i=0;i<L_;i++){
    k_ln<1><<<MT/4, 256, 0, stream>>>(xbuf, tmp, l_ln1g+i*D_, l_ln1b+i*D_, MT, lens, 0);
    k_gemm<<<dim3(10,50), 256, 0, stream>>>(tmp, l_win+(size_t)i*D_*640, l_bin+i*640, proj,
                                            MT, 640, 256, 256, 640, 0);
    k_attn<<<B_*H_, 64, 0, stream>>>(proj, lens, attn);
    k_gemm<<<dim3(4,50), 256, 0, stream>>>(attn, l_wc+(size_t)i*128*256, l_bc+i*256, cat,
                                           MT, 256, 128, 128, 768, 0);
    k_dwconv<<<MT, 256, 0, stream>>>(tmp, l_tw+i*768, l_tb+i*256, l_pw+i*1280, l_pb+i*256, cat);
    k_gemm<<<dim3(4,50), 256, 0, stream>>>(cat, l_wmix+(size_t)i*768*256, l_bmix+i*256, tmp,
                                           MT, 256, 768, 768, 256, 0);
    k_postmix<<<MT, 256, 0, stream>>>(xbuf, proj, tmp, lens);
    k_ln<1><<<MT/4, 256, 0, stream>>>(xbuf, cat, l_ln2g+i*D_, l_ln2b+i*D_, MT, lens, 0);
    k_gemm<<<dim3(16,50), 256, 0, stream>>>(cat, l_wf1+(size_t)i*D_*FF_, l_bf1+i*FF_, mid,
                                            MT, FF_, 256, 256, FF_, 1);
    k_gemm<<<dim3(4,50), 256, 0, stream>>>(mid, l_wf2+(size_t)i*FF_*D_, l_bf2+i*D_, tmp,
                                           MT, 256, 1024, 1024, 256, 0);
    k_addmask<<<MT, 256, 0, stream>>>(xbuf, tmp, lens);
  }

  // ---- final LN + pooling + user head ----
  k_ln<1><<<MT/4, 256, 0, stream>>>(xbuf, xbuf, fn_g, fn_b, MT, lens, 1);
  k_pool<<<B_, 256, 0, stream>>>(xbuf, lens, pg_w, pg_b, u0);
  k_gemm<<<dim3(16,1), 256, 0, stream>>>(u0, uh_w1, uh_b1, u1, 32, 1024, 768, 768, 1024, 1);
  k_ln<4><<<8, 256, 0, stream>>>(u1, u1, uh_lng, uh_lnb, 32, lens, 0);
  k_gemm<<<dim3(4,1), 256, 0, stream>>>(u1, uh_w2, uh_b2, u2, 32, 256, 1024, 1024, 256, 0);
  k_norm<<<B_, 64, 0, stream>>>(u2);

  // ---- scoring ----
  k_score<<<(NI_+255)/256, 256, 0, stream>>>(u2, item_emb, item_bias, out);
}

// Round 2
// 2801.877 us; speedup vs baseline: 2.2239x; 2.2239x over previous
//
#include <hip/hip_runtime.h>
#include <math.h>

#define B_ 32
#define T_ 200
#define D_ 256
#define H_ 4
#define DH_ 32
#define INNER_ 128
#define L_ 8
#define FF_ 1024
#define NI_ 100000
#define NB_ 64

typedef __attribute__((ext_vector_type(8))) short short8;
typedef __attribute__((ext_vector_type(8))) unsigned short ushort8;
typedef __attribute__((ext_vector_type(4))) float floatx4;

__device__ __forceinline__ float gelu_f(float x){
  return 0.5f*x*(1.0f+erff(x*0.70710678118654752f));
}
__device__ __forceinline__ float wsum(float v){
  #pragma unroll
  for (int o=32;o>0;o>>=1) v += __shfl_xor(v,o,64);
  return v;
}
__device__ __forceinline__ unsigned short f2bf(float x){
  unsigned int u = __float_as_uint(x);
  unsigned int r = (u + 0x7fffu + ((u>>16)&1u)) >> 16;
  return (unsigned short)r;
}

// ---------------- weight fp32 [K][N] -> bf16 W^T [N][K], 32x32 LDS transpose ----------------
__device__ __forceinline__ void cvt_tile(const float* __restrict__ src, unsigned short* __restrict__ dst,
                                         int K, int N, int tk, int tn, int tid, float (*s)[33])
{
  int tx = tid & 31, ty0 = tid >> 5;
  #pragma unroll
  for (int it=0; it<4; ++it){
    int ty = ty0 + it*8;
    s[ty][tx] = src[(size_t)(tk*32+ty)*N + tn*32+tx];
  }
  __syncthreads();
  #pragma unroll
  for (int it=0; it<4; ++it){
    int ty = ty0 + it*8;
    dst[(size_t)(tn*32+ty)*K + tk*32 + tx] = f2bf(s[tx][ty]);
  }
}

// per-layer: win(256x640) wc(128x256) wmix(768x256) wf1(256x1024) wf2(1024x256)
__global__ __launch_bounds__(256) void k_cvtL(
  const float* __restrict__ win, const float* __restrict__ wc, const float* __restrict__ wmix,
  const float* __restrict__ wf1, const float* __restrict__ wf2, unsigned short* __restrict__ dst)
{
  __shared__ float s[32][33];
  int b = blockIdx.x, tid = threadIdx.x;
  if (b < 160){        int t=b;       cvt_tile(win,  dst,          256, 640, t/20, t%20, tid, s); }
  else if (b < 192){   int t=b-160;   cvt_tile(wc,   dst+163840,   128, 256, t/8,  t%8,  tid, s); }
  else if (b < 384){   int t=b-192;   cvt_tile(wmix, dst+196608,   768, 256, t/8,  t%8,  tid, s); }
  else if (b < 640){   int t=b-384;   cvt_tile(wf1,  dst+393216,   256, 1024,t/32, t%32, tid, s); }
  else {               int t=b-640;   cvt_tile(wf2,  dst+655360,   1024,256, t/8,  t%8,  tid, s); }
}

// head: tf_w2(256x256) uh_w1(768x1024) uh_w2(1024x256)
__global__ __launch_bounds__(256) void k_cvtH(
  const float* __restrict__ tfw2, const float* __restrict__ uhw1, const float* __restrict__ uhw2,
  unsigned short* __restrict__ dst)
{
  __shared__ float s[32][33];
  int b = blockIdx.x, tid = threadIdx.x;
  if (b < 64){         int t=b;       cvt_tile(tfw2, dst,          256, 256, t/8,  t%8,  tid, s); }
  else if (b < 832){   int t=b-64;    cvt_tile(uhw1, dst+65536,    768, 1024,t/32, t%32, tid, s); }
  else {               int t=b-832;   cvt_tile(uhw2, dst+851968,   1024,256, t/8,  t%8,  tid, s); }
}

// ---------------- bf16 MFMA GEMM: C[M,N] = A[M,K](fp32) @ W^T[N,K](bf16) ----------------
// tile 128x128, 4 waves 2x2, wave 64x64 = 4x4 of 16x16x32 MFMA
// mode: 0 = +bias; 1 = gelu(+bias); 2 = +bias + existing C
__global__ __launch_bounds__(256) void k_gemm_bf(
    const float* __restrict__ A, const unsigned short* __restrict__ Wt,
    const float* __restrict__ bias, float* __restrict__ C,
    int M, int N, int K, int ldA, int ldC, int mode)
{
  __shared__ unsigned short Als[128][40];
  __shared__ unsigned short Bls[128][40];
  int tid = threadIdx.x;
  int wave = tid >> 6, lane = tid & 63;
  int wm = (wave >> 1) * 64, wn = (wave & 1) * 64;
  int frow = lane & 15, kg = lane >> 4;
  int bm = blockIdx.y * 128, bn = blockIdx.x * 128;
  // staging indices: thread -> (row, k-half)
  int sm = tid >> 1, skh = (tid & 1) * 16;

  floatx4 acc[4][4];
  #pragma unroll
  for (int i=0;i<4;i++)
    #pragma unroll
    for (int j=0;j<4;j++) acc[i][j] = (floatx4){0.f,0.f,0.f,0.f};

  for (int k0=0; k0<K; k0+=32){
    // ---- stage A: 128 rows x 32 k, fp32 -> bf16 ----
    {
      int gm = bm + sm;
      float f[16];
      if (gm < M){
        const float4* ap = (const float4*)(A + (size_t)gm*ldA + k0 + skh);
        #pragma unroll
        for (int c=0;c<4;c++){ float4 v = ap[c]; f[c*4]=v.x; f[c*4+1]=v.y; f[c*4+2]=v.z; f[c*4+3]=v.w; }
      } else {
        #pragma unroll
        for (int c=0;c<16;c++) f[c]=0.f;
      }
      ushort8 pa, pb;
      #pragma unroll
      for (int c=0;c<8;c++){ pa[c]=f2bf(f[c]); pb[c]=f2bf(f[8+c]); }
      *(ushort8*)&Als[sm][skh]   = pa;
      *(ushort8*)&Als[sm][skh+8] = pb;
    }
    // ---- stage B: 128 n-rows x 32 k, bf16 ----
    {
      int gn = bn + sm;
      ushort8 wa, wb;
      if (gn < N){
        const ushort8* wp = (const ushort8*)(Wt + (size_t)gn*K + k0 + skh);
        wa = wp[0]; wb = wp[1];
      } else {
        #pragma unroll
        for (int c=0;c<8;c++){ wa[c]=0; wb[c]=0; }
      }
      *(ushort8*)&Bls[sm][skh]   = wa;
      *(ushort8*)&Bls[sm][skh+8] = wb;
    }
    __syncthreads();
    short8 af[4], bf[4];
    #pragma unroll
    for (int i=0;i<4;i++) af[i] = *(const short8*)&Als[wm + 16*i + frow][kg*8];
    #pragma unroll
    for (int j=0;j<4;j++) bf[j] = *(const short8*)&Bls[wn + 16*j + frow][kg*8];
    #pragma unroll
    for (int i=0;i<4;i++)
      #pragma unroll
      for (int j=0;j<4;j++)
        acc[i][j] = __builtin_amdgcn_mfma_f32_16x16x32_bf16(af[i], bf[j], acc[i][j], 0, 0, 0);
    __syncthreads();
  }

  // ---- epilogue: D row = kg*4 + r, col = frow ----
  #pragma unroll
  for (int j=0;j<4;j++){
    int n = bn + wn + 16*j + frow;
    float bv = bias[n];
    #pragma unroll
    for (int i=0;i<4;i++){
      int m0 = bm + wm + 16*i + kg*4;
      #pragma unroll
      for (int r=0;r<4;r++){
        int m = m0 + r;
        if (m < M){
          float v = acc[i][j][r] + bv;
          if (mode == 1) v = gelu_f(v);
          float* cp = &C[(size_t)m*ldC + n];
          if (mode == 2) v += *cp;
          *cp = v;
        }
      }
    }
  }
}

// ---------------- embedding + time features ----------------
__global__ __launch_bounds__(256) void k_embed(
  const int* __restrict__ ids, const int* __restrict__ ts, const int* __restrict__ lens,
  const float* __restrict__ item_emb, const float* __restrict__ pos_emb,
  const float* __restrict__ gap_emb, const float* __restrict__ rec_emb,
  const float* __restrict__ tf_w1, const float* __restrict__ tf_b1,
  float* __restrict__ xbuf, float* __restrict__ tfh)
{
  int bt = blockIdx.x;
  int b = bt / T_, t = bt % T_;
  int d = threadIdx.x;
  int len = lens[b];
  int tcur = ts[b*T_+t];
  int tlast = ts[b*T_+T_-1];
  bool mask  = t >= T_ - len;
  bool pmask = (t >= 1) && ((t-1) >= T_ - len);
  int gap = 0;
  if (mask && pmask){ int pv = ts[b*T_+t-1]; gap = max(tcur - pv, 0); }
  int rec = mask ? max(tlast - tcur, 0) : 0;
  int gb = min(max((int)floorf(log2f((float)gap + 1.0f)), 0), NB_-1);
  int rb = min(max((int)floorf(log2f((float)rec + 1.0f)), 0), NB_-1);
  float rec_raw = (float)max(tlast - tcur, 0);
  float tf0 = log1pf((float)gb);
  float tf1 = log1pf(rec_raw);
  float hid = gelu_f(tf0*tf_w1[d] + tf1*tf_w1[D_+d] + tf_b1[d]);
  tfh[(size_t)bt*D_ + d] = hid;
  int id = ids[b*T_+t];
  xbuf[(size_t)bt*D_ + d] = item_emb[(size_t)id*D_ + d] + pos_emb[t*D_ + d]
                          + gap_emb[gb*D_ + d] + rec_emb[rb*D_ + d];
}

// ---------------- LayerNorm (wave per row) ----------------
template<int NC>
__global__ __launch_bounds__(256) void k_ln(
  const float* __restrict__ in, float* __restrict__ out,
  const float* __restrict__ g, const float* __restrict__ bb,
  int rows, const int* __restrict__ lens, int applyMask)
{
  int wid = threadIdx.x >> 6, lane = threadIdx.x & 63;
  int r = blockIdx.x*4 + wid;
  if (r >= rows) return;
  const int D = NC*256;
  const float4* rp = (const float4*)(in + (size_t)r*D);
  float4 v[NC];
  float s = 0.f;
  #pragma unroll
  for (int c=0;c<NC;c++){ v[c] = rp[c*64 + lane]; s += v[c].x+v[c].y+v[c].z+v[c].w; }
  s = wsum(s);
  float mean = s / (float)D;
  float q = 0.f;
  #pragma unroll
  for (int c=0;c<NC;c++){
    float a=v[c].x-mean, b2=v[c].y-mean, c2=v[c].z-mean, d2=v[c].w-mean;
    q += a*a + b2*b2 + c2*c2 + d2*d2;
  }
  q = wsum(q);
  float rstd = rsqrtf(q/(float)D + 1e-5f);
  float m = 1.f;
  if (applyMask){ int t = r % T_; int b = r / T_; m = (t >= T_ - lens[b]) ? 1.f : 0.f; }
  float4* op = (float4*)(out + (size_t)r*D);
  #pragma unroll
  for (int c=0;c<NC;c++){
    float4 gg  = ((const float4*)g )[c*64+lane];
    float4 bv  = ((const float4*)bb)[c*64+lane];
    float4 o;
    o.x = ((v[c].x-mean)*rstd*gg.x + bv.x)*m;
    o.y = ((v[c].y-mean)*rstd*gg.y + bv.y)*m;
    o.z = ((v[c].z-mean)*rstd*gg.z + bv.z)*m;
    o.w = ((v[c].w-mean)*rstd*gg.w + bv.w)*m;
    op[c*64+lane] = o;
  }
}

// ---------------- causal linear attention ----------------
#define CH_ 25
__global__ __launch_bounds__(64) void k_attn(
  const float* __restrict__ proj, const int* __restrict__ lens, float* __restrict__ attn)
{
  int bh = blockIdx.x; int b = bh >> 2, h = bh & 3;
  int lane = threadIdx.x; int e = lane & 31; int half = lane >> 5;
  int tstart = T_ - lens[b];
  __shared__ float sq[CH_*32], sk[CH_*32], sv[CH_*32];
  float kv[16]; float kp[16];
  #pragma unroll
  for (int j=0;j<16;j++){ kv[j]=0.f; kp[j]=0.f; }
  for (int c=0;c<T_/CH_;c++){
    int t0 = c*CH_;
    __syncthreads();
    for (int idx=lane; idx<CH_*32; idx+=64){
      int tl = idx >> 5, dd = idx & 31;
      int t = t0 + tl;
      float m = (t >= tstart) ? 1.f : 0.f;
      const float* pr = proj + (size_t)(b*T_+t)*640 + h*32 + dd;
      float qv = pr[256], kw = pr[384], vv = pr[512];
      qv = (qv > 0.f ? qv + 1.f : __expf(qv)) * m;
      kw = (kw > 0.f ? kw + 1.f : __expf(kw)) * m;
      sq[idx] = qv; sk[idx] = kw; sv[idx] = vv * m;
    }
    __syncthreads();
    for (int tl=0; tl<CH_; tl++){
      const float4* q4 = (const float4*)(sq + tl*32 + half*16);
      const float4* k4 = (const float4*)(sk + tl*32 + half*16);
      float vf = sv[tl*32 + e];
      float num=0.f, den=0.f, qk=0.f;
      #pragma unroll
      for (int jj=0;jj<4;jj++){
        float4 qq = q4[jj]; float4 kk = k4[jj];
        int j = jj*4;
        num += qq.x*kv[j] + qq.y*kv[j+1] + qq.z*kv[j+2] + qq.w*kv[j+3];
        den += qq.x*kp[j] + qq.y*kp[j+1] + qq.z*kp[j+2] + qq.w*kp[j+3];
        qk  += qq.x*kk.x + qq.y*kk.y + qq.z*kk.z + qq.w*kk.w;
        kv[j]   += kk.x*vf; kv[j+1] += kk.y*vf; kv[j+2] += kk.z*vf; kv[j+3] += kk.w*vf;
        kp[j]   += kk.x;    kp[j+1] += kk.y;    kp[j+2] += kk.z;    kp[j+3] += kk.w;
      }
      num += __shfl_xor(num,32,64);
      den += __shfl_xor(den,32,64);
      qk  += __shfl_xor(qk ,32,64);
      int t = t0 + tl;
      float m = (t >= tstart) ? 1.f : 0.f;
      num += qk * vf;
      den += qk;
      float o = num/(den + 1e-6f)*m;
      if (half == 0) attn[(size_t)(b*T_+t)*128 + h*32 + e] = o;
    }
  }
}

// ---------------- depthwise causal convs ----------------
__global__ __launch_bounds__(256) void k_dwconv(
  const float* __restrict__ nrm, const float* __restrict__ tw, const float* __restrict__ tb,
  const float* __restrict__ pw, const float* __restrict__ pb, float* __restrict__ cat)
{
  int idx = blockIdx.x*256 + threadIdx.x;
  int d = idx & 255; int bt = idx >> 8; int t = bt % T_;
  float xs[5];
  #pragma unroll
  for (int j=0;j<5;j++){
    int tt = t - 4 + j;
    xs[j] = (tt >= 0) ? nrm[(size_t)(bt - 4 + j)*D_ + d] : 0.f;
  }
  float tmp = tw[d*3+0]*xs[2] + tw[d*3+1]*xs[3] + tw[d*3+2]*xs[4] + tb[d];
  float pos = pb[d];
  #pragma unroll
  for (int j=0;j<5;j++) pos += pw[d*5+j]*xs[j];
  cat[(size_t)bt*768 + 256 + d] = tmp;
  cat[(size_t)bt*768 + 512 + d] = pos;
}

// ---------------- gated residual ----------------
__global__ __launch_bounds__(256) void k_postmix(
  float* __restrict__ x, const float* __restrict__ proj, const float* __restrict__ mixed,
  const int* __restrict__ lens)
{
  int idx = blockIdx.x*256 + threadIdx.x;
  int d = idx & 255; int bt = idx >> 8; int t = bt % T_, b = bt / T_;
  float m = (t >= T_ - lens[b]) ? 1.f : 0.f;
  float g = proj[(size_t)bt*640 + d];
  float s = 1.f/(1.f + __expf(-g));
  x[idx] = (x[idx] + s*mixed[idx])*m;
}

__global__ __launch_bounds__(256) void k_addmask(
  float* __restrict__ x, const float* __restrict__ f, const int* __restrict__ lens)
{
  int idx = blockIdx.x*256 + threadIdx.x;
  int bt = idx >> 8; int t = bt % T_, b = bt / T_;
  float m = (t >= T_ - lens[b]) ? 1.f : 0.f;
  x[idx] = (x[idx] + f[idx])*m;
}

// ---------------- pooling ----------------
__global__ __launch_bounds__(256) void k_pool(
  const float* __restrict__ x, const int* __restrict__ lens,
  const float* __restrict__ pg_w, const float* __restrict__ pg_b,
  float* __restrict__ u0)
{
  int b = blockIdx.x;
  int tid = threadIdx.x, wid = tid>>6, lane = tid&63;
  __shared__ float sps[T_];
  __shared__ float spw[T_];
  int len = lens[b]; int tstart = T_ - len;
  const float4* pw4 = (const float4*)pg_w;
  float4 wv = pw4[lane];
  for (int t = wid; t < T_; t += 4){
    const float4* xr = (const float4*)(x + (size_t)(b*T_+t)*D_);
    float4 xv = xr[lane];
    float dot = xv.x*wv.x + xv.y*wv.y + xv.z*wv.z + xv.w*wv.w;
    dot = wsum(dot);
    if (lane==0) sps[t] = (t >= tstart) ? dot + pg_b[0] : -1e9f;
  }
  __syncthreads();
  float mx = -1e30f;
  for (int t=0;t<T_;t++) mx = fmaxf(mx, sps[t]);
  float sum = 0.f;
  for (int t=0;t<T_;t++) sum += __expf(sps[t]-mx);
  float inv = 1.f/sum;
  if (tid < T_) spw[tid] = __expf(sps[tid]-mx)*inv;
  __syncthreads();
  int d = tid;
  float macc=0.f, aacc=0.f;
  for (int t=0;t<T_;t++){
    float v = x[(size_t)(b*T_+t)*D_ + d];
    macc += v;
    aacc += spw[t]*v;
  }
  u0[b*768 + d]       = x[(size_t)(b*T_+T_-1)*D_ + d];
  u0[b*768 + 256 + d] = macc / (float)max(len,1);
  u0[b*768 + 512 + d] = aacc;
}

// ---------------- normalize u rows ----------------
__global__ __launch_bounds__(64) void k_norm(float* __restrict__ u)
{
  int b = blockIdx.x; int lane = threadIdx.x;
  float4* r = (float4*)(u + b*256);
  float4 v = r[lane];
  float ss = v.x*v.x + v.y*v.y + v.z*v.z + v.w*v.w;
  ss = wsum(ss);
  float sc = 1.f/fmaxf(sqrtf(ss), 1e-12f);
  v.x*=sc; v.y*=sc; v.z*=sc; v.w*=sc;
  r[lane]=v;
}

// ---------------- scoring ----------------
__global__ __launch_bounds__(256) void k_score(
  const float* __restrict__ u, const float* __restrict__ item_emb,
  const float* __restrict__ item_bias, float* __restrict__ out)
{
  __shared__ float su[D_][B_];
  __shared__ float Wt[16][260];
  int tid = threadIdx.x;
  for (int i = tid; i < B_*D_; i += 256){
    int b = i & 31, k = i >> 5;
    su[k][b] = u[b*D_ + k];
  }
  int n0 = blockIdx.x * 256;
  int n = n0 + tid;
  float acc[B_];
  #pragma unroll
  for (int b=0;b<B_;b++) acc[b]=0.f;
  float ss = 0.f;
  for (int k0=0; k0<D_; k0+=16){
    __syncthreads();
    for (int i = tid; i < 256*16; i += 256){
      int il = i >> 4, kk = i & 15;
      int ni = n0 + il;
      float v = 0.f;
      if (ni < NI_) v = item_emb[(size_t)(ni+1)*D_ + k0 + kk];
      Wt[kk][il] = v;
    }
    __syncthreads();
    #pragma unroll
    for (int kk=0;kk<16;kk++){
      float wv = Wt[kk][tid];
      ss += wv*wv;
      const float4* su4 = (const float4*)su[k0+kk];
      #pragma unroll
      for (int b4=0;b4<8;b4++){
        float4 uu = su4[b4];
        acc[b4*4+0] += uu.x*wv;
        acc[b4*4+1] += uu.y*wv;
        acc[b4*4+2] += uu.z*wv;
        acc[b4*4+3] += uu.w*wv;
      }
    }
  }
  if (n < NI_){
    float sc = 1.f/fmaxf(sqrtf(ss), 1e-12f);
    float bias = item_bias[n+1];
    #pragma unroll
    for (int b=0;b<B_;b++){
      out[(size_t)b*NI_ + n] = acc[b]*sc + bias;
    }
  }
}

extern "C" void kernel_launch(void* const* d_in, const int* in_sizes, int n_in,
                              void* d_out, int out_size, void* d_ws, size_t ws_size,
                              hipStream_t stream)
{
  const int* ids  = (const int*)d_in[0];
  const int* ts   = (const int*)d_in[1];
  const int* lens = (const int*)d_in[2];
  const float* item_emb = (const float*)d_in[3];
  const float* pos_emb  = (const float*)d_in[4];
  const float* gap_emb  = (const float*)d_in[5];
  const float* rec_emb  = (const float*)d_in[6];
  const float* tf_w1 = (const float*)d_in[7];
  const float* tf_b1 = (const float*)d_in[8];
  const float* tf_w2 = (const float*)d_in[9];
  const float* tf_b2 = (const float*)d_in[10];
  const float* in_g  = (const float*)d_in[11];
  const float* in_b  = (const float*)d_in[12];
  const float* l_ln1g = (const float*)d_in[13];
  const float* l_ln1b = (const float*)d_in[14];
  const float* l_win  = (const float*)d_in[15];
  const float* l_bin  = (const float*)d_in[16];
  const float* l_wc   = (const float*)d_in[17];
  const float* l_bc   = (const float*)d_in[18];
  const float* l_tw   = (const float*)d_in[19];
  const float* l_tb   = (const float*)d_in[20];
  const float* l_pw   = (const float*)d_in[21];
  const float* l_pb   = (const float*)d_in[22];
  const float* l_wmix = (const float*)d_in[23];
  const float* l_bmix = (const float*)d_in[24];
  const float* l_ln2g = (const float*)d_in[25];
  const float* l_ln2b = (const float*)d_in[26];
  const float* l_wf1  = (const float*)d_in[27];
  const float* l_bf1  = (const float*)d_in[28];
  const float* l_wf2  = (const float*)d_in[29];
  const float* l_bf2  = (const float*)d_in[30];
  const float* fn_g = (const float*)d_in[31];
  const float* fn_b = (const float*)d_in[32];
  const float* pg_w = (const float*)d_in[33];
  const float* pg_b = (const float*)d_in[34];
  const float* uh_w1 = (const float*)d_in[35];
  const float* uh_b1 = (const float*)d_in[36];
  const float* uh_lng = (const float*)d_in[37];
  const float* uh_lnb = (const float*)d_in[38];
  const float* uh_w2 = (const float*)d_in[39];
  const float* uh_b2 = (const float*)d_in[40];
  const float* item_bias = (const float*)d_in[41];
  float* out = (float*)d_out;

  const int MT = B_*T_;
  float* ws   = (float*)d_ws;
  float* xbuf = ws;
  float* tmp  = xbuf + (size_t)MT*D_;
  float* proj = tmp  + (size_t)MT*D_;
  float* attn = proj + (size_t)MT*640;
  float* cat  = attn + (size_t)MT*128;
  float* mid  = cat  + (size_t)MT*768;
  float* u0   = mid  + (size_t)MT*FF_;
  float* u1   = u0 + 32*768;
  float* u2   = u1 + 32*1024;
  unsigned short* WtL = (unsigned short*)(u2 + 32*256);   // 917504 ushorts, reused per layer
  unsigned short* WtH = WtL + 917504;                     // 1114112 ushorts, persistent

  // ---- head/front weight conversion ----
  k_cvtH<<<1088, 256, 0, stream>>>(tf_w2, uh_w1, uh_w2, WtH);

  // ---- embedding + dense time ----
  k_embed<<<MT, 256, 0, stream>>>(ids, ts, lens, item_emb, pos_emb, gap_emb, rec_emb,
                                  tf_w1, tf_b1, xbuf, tmp);
  k_gemm_bf<<<dim3(2,50), 256, 0, stream>>>(tmp, WtH, tf_b2, xbuf, MT, 256, 256, 256, 256, 2);
  k_ln<1><<<MT/4, 256, 0, stream>>>(xbuf, xbuf, in_g, in_b, MT, lens, 1);

  // ---- layers ----
  for (int i=0;i<L_;i++){
    k_cvtL<<<896, 256, 0, stream>>>(l_win+(size_t)i*D_*640, l_wc+(size_t)i*128*256,
                                    l_wmix+(size_t)i*768*256, l_wf1+(size_t)i*D_*FF_,
                                    l_wf2+(size_t)i*FF_*D_, WtL);
    k_ln<1><<<MT/4, 256, 0, stream>>>(xbuf, tmp, l_ln1g+i*D_, l_ln1b+i*D_, MT, lens, 0);
    k_gemm_bf<<<dim3(5,50), 256, 0, stream>>>(tmp, WtL, l_bin+i*640, proj,
                                              MT, 640, 256, 256, 640, 0);
    k_attn<<<B_*H_, 64, 0, stream>>>(proj, lens, attn);
    k_gemm_bf<<<dim3(2,50), 256, 0, stream>>>(attn, WtL+163840, l_bc+i*256, cat,
                                              MT, 256, 128, 128, 768, 0);
    k_dwconv<<<MT, 256, 0, stream>>>(tmp, l_tw+i*768, l_tb+i*256, l_pw+i*1280, l_pb+i*256, cat);
    k_gemm_bf<<<dim3(2,50), 256, 0, stream>>>(cat, WtL+196608, l_bmix+i*256, tmp,
                                              MT, 256, 768, 768, 256, 0);
    k_postmix<<<MT, 256, 0, stream>>>(xbuf, proj, tmp, lens);
    k_ln<1><<<MT/4, 256, 0, stream>>>(xbuf, cat, l_ln2g+i*D_, l_ln2b+i*D_, MT, lens, 0);
    k_gemm_bf<<<dim3(8,50), 256, 0, stream>>>(cat, WtL+393216, l_bf1+i*FF_, mid,
                                              MT, FF_, 256, 256, FF_, 1);
    k_gemm_bf<<<dim3(2,50), 256, 0, stream>>>(mid, WtL+655360, l_bf2+i*D_, tmp,
                                              MT, 256, 1024, 1024, 256, 0);
    k_addmask<<<MT, 256, 0, stream>>>(xbuf, tmp, lens);
  }

  // ---- final LN + pooling + user head ----
  k_ln<1><<<MT/4, 256, 0, stream>>>(xbuf, xbuf, fn_g, fn_b, MT, lens, 1);
  k_pool<<<B_, 256, 0, stream>>>(xbuf, lens, pg_w, pg_b, u0);
  k_gemm_bf<<<dim3(8,1), 256, 0, stream>>>(u0, WtH+65536, uh_b1, u1, 32, 1024, 768, 768, 1024, 1);
  k_ln<4><<<8, 256, 0, stream>>>(u1, u1, uh_lng, uh_lnb, 32, lens, 0);
  k_gemm_bf<<<dim3(2,1), 256, 0, stream>>>(u1, WtH+851968, uh_b2, u2, 32, 256, 1024, 1024, 256, 0);
  k_norm<<<B_, 64, 0, stream>>>(u2);

  // ---- scoring ----
  k_score<<<(NI_+255)/256, 256, 0, stream>>>(u2, item_emb, item_bias, out);
}

// Round 4
// 2421.066 us; speedup vs baseline: 2.5737x; 1.1573x over previous
//
#include <hip/hip_runtime.h>
#include <math.h>

#define B_ 32
#define T_ 200
#define D_ 256
#define H_ 4
#define DH_ 32
#define INNER_ 128
#define L_ 8
#define FF_ 1024
#define NI_ 100000
#define NB_ 64

typedef __attribute__((ext_vector_type(8))) short short8;
typedef __attribute__((ext_vector_type(8))) unsigned short ushort8;
typedef __attribute__((ext_vector_type(4))) float floatx4;

__device__ __forceinline__ float gelu_f(float x){
  return 0.5f*x*(1.0f+erff(x*0.70710678118654752f));
}
__device__ __forceinline__ float wsum(float v){
  #pragma unroll
  for (int o=32;o>0;o>>=1) v += __shfl_xor(v,o,64);
  return v;
}
__device__ __forceinline__ unsigned short f2bf(float x){
  unsigned int u = __float_as_uint(x);
  unsigned int r = (u + 0x7fffu + ((u>>16)&1u)) >> 16;
  return (unsigned short)r;
}

// ---------------- weight fp32 [K][N] -> bf16 W^T [N][K] tile transpose ----------------
__device__ __forceinline__ void cvt_tile(const float* __restrict__ src, unsigned short* __restrict__ dst,
                                         int K, int N, int tk, int tn, int tid, float (*s)[33])
{
  int tx = tid & 31, ty0 = tid >> 5;
  #pragma unroll
  for (int it=0; it<4; ++it){
    int ty = ty0 + it*8;
    s[ty][tx] = src[(size_t)(tk*32+ty)*N + tn*32+tx];
  }
  __syncthreads();
  #pragma unroll
  for (int it=0; it<4; ++it){
    int ty = ty0 + it*8;
    dst[(size_t)(tn*32+ty)*K + tk*32 + tx] = f2bf(s[tx][ty]);
  }
}

// ALL weight conversions in one dispatch.
__global__ __launch_bounds__(256) void k_cvtAll(
  const float* __restrict__ win, const float* __restrict__ wmix,
  const float* __restrict__ wf1, const float* __restrict__ wf2,
  const float* __restrict__ tfw2, const float* __restrict__ uhw1, const float* __restrict__ uhw2,
  unsigned short* __restrict__ WtPerm, unsigned short* __restrict__ WtMixT,
  unsigned short* __restrict__ WtH)
{
  __shared__ float s[32][33];
  int b = blockIdx.x, tid = threadIdx.x;
  if (b < 6912){
    int l = b / 864, r = b % 864;
    if (r < 160)      cvt_tile(win + (size_t)l*163840, WtPerm + (size_t)l*688128,          256, 640,  r/20,      r%20,      tid, s);
    else if (r < 352){int t=r-160; cvt_tile(wmix + (size_t)l*196608, WtMixT + (size_t)l*196608, 768, 256, t/8, t%8, tid, s);}
    else if (r < 608){int t=r-352; cvt_tile(wf1 + (size_t)l*262144, WtPerm + (size_t)l*688128 + 163840, 256, 1024, t/32, t%32, tid, s);}
    else             {int t=r-608; cvt_tile(wf2 + (size_t)l*262144, WtPerm + (size_t)l*688128 + 425984, 1024, 256, t/8, t%8, tid, s);}
  } else {
    int r = b - 6912;
    if (r < 64)       cvt_tile(tfw2, WtH,        256, 256,  r/8,  r%8,  tid, s);
    else if (r < 832){int t=r-64;  cvt_tile(uhw1, WtH+65536,  768, 1024, t/32, t%32, tid, s);}
    else             {int t=r-832; cvt_tile(uhw2, WtH+851968, 1024, 256, t/8,  t%8,  tid, s);}
  }
}

// assemble WtBig[l][256 n][640 k]: k<128 from WcombF^T, k>=128 copy wmixT (d=k+128)
__global__ __launch_bounds__(256) void k_asm(
  const float* __restrict__ WcombF, const unsigned short* __restrict__ WtMixT,
  unsigned short* __restrict__ WtBig)
{
  int l = blockIdx.x >> 3, g = blockIdx.x & 7;
  int tid = threadIdx.x;
  int n = g*32 + (tid >> 3);
  int k0 = (tid & 7) * 80;
  const float* wc = WcombF + (size_t)l*32768;
  const unsigned short* wm = WtMixT + (size_t)l*196608 + (size_t)n*768;
  unsigned short* dst = WtBig + (size_t)l*163840 + (size_t)n*640;
  for (int kk=0; kk<80; kk++){
    int k = k0 + kk;
    dst[k] = (k < 128) ? f2bf(wc[(size_t)k*256 + n]) : wm[k+128];
  }
}

// bmixP[l][n] = bmix[l][n] + sum_d bc[l][d] * wmix[l][d][n]
__global__ __launch_bounds__(256) void k_bfold(
  const float* __restrict__ bc, const float* __restrict__ bmix,
  const float* __restrict__ wmix, float* __restrict__ bmixP)
{
  int l = blockIdx.x; int n = threadIdx.x;
  const float* w = wmix + (size_t)l*196608;
  const float* c = bc + l*256;
  float s = bmix[l*256 + n];
  for (int d=0; d<256; d++) s += c[d]*w[(size_t)d*256 + n];
  bmixP[l*256+n] = s;
}

// ---------------- bf16 MFMA GEMM: C[M,N] = A[M,K](fp32) @ W^T[N,K](bf16) ----------------
// block tile 128 x TN; 4 waves 2x2; wave tile 64 x TN/2
// mode: 0 = +bias; 1 = gelu(+bias); 2 = +bias + existing C
template<int TN>
__global__ __launch_bounds__(256) void k_gemm_bf(
    const float* __restrict__ A, const unsigned short* __restrict__ Wt,
    const float* __restrict__ bias, float* __restrict__ C,
    int M, int N, int K, int ldA, int ldW, int ldC, int mode,
    size_t sA, size_t sW, size_t sC, size_t sB)
{
  constexpr int NJ = TN/32;            // N-frags per wave
  __shared__ unsigned short Als[128][40];
  __shared__ unsigned short Bls[TN][40];
  int z = blockIdx.z;
  A += (size_t)z*sA; Wt += (size_t)z*sW; C += (size_t)z*sC;
  const float* bz = bias ? bias + (size_t)z*sB : nullptr;
  int tid = threadIdx.x;
  int wave = tid >> 6, lane = tid & 63;
  int wm = (wave >> 1) * 64, wn = (wave & 1) * (TN/2);
  int frow = lane & 15, kg = lane >> 4;
  int bm = blockIdx.y * 128, bn = blockIdx.x * TN;
  int sm = tid >> 1, skh = (tid & 1) * 16;

  floatx4 acc[4][NJ];
  #pragma unroll
  for (int i=0;i<4;i++)
    #pragma unroll
    for (int j=0;j<NJ;j++) acc[i][j] = (floatx4){0.f,0.f,0.f,0.f};

  for (int k0=0; k0<K; k0+=32){
    {
      int gm = bm + sm;
      float f[16];
      if (gm < M){
        const float4* ap = (const float4*)(A + (size_t)gm*ldA + k0 + skh);
        #pragma unroll
        for (int c=0;c<4;c++){ float4 v = ap[c]; f[c*4]=v.x; f[c*4+1]=v.y; f[c*4+2]=v.z; f[c*4+3]=v.w; }
      } else {
        #pragma unroll
        for (int c=0;c<16;c++) f[c]=0.f;
      }
      ushort8 pa, pb;
      #pragma unroll
      for (int c=0;c<8;c++){ pa[c]=f2bf(f[c]); pb[c]=f2bf(f[8+c]); }
      *(ushort8*)&Als[sm][skh]   = pa;
      *(ushort8*)&Als[sm][skh+8] = pb;
    }
    #pragma unroll
    for (int u=0; u<TN/64; u++){
      int li = tid + u*256;
      int row = li >> 2, koff = (li & 3) * 8;
      int gn = bn + row;
      ushort8 wv;
      if (gn < N){
        wv = *(const ushort8*)&Wt[(size_t)gn*ldW + k0 + koff];
      } else {
        for (int c=0;c<8;c++) wv[c]=0;
      }
      *(ushort8*)&Bls[row][koff] = wv;
    }
    __syncthreads();
    short8 af[4], bf[NJ];
    #pragma unroll
    for (int i=0;i<4;i++) af[i] = *(const short8*)&Als[wm + 16*i + frow][kg*8];
    #pragma unroll
    for (int j=0;j<NJ;j++) bf[j] = *(const short8*)&Bls[wn + 16*j + frow][kg*8];
    #pragma unroll
    for (int i=0;i<4;i++)
      #pragma unroll
      for (int j=0;j<NJ;j++)
        acc[i][j] = __builtin_amdgcn_mfma_f32_16x16x32_bf16(af[i], bf[j], acc[i][j], 0, 0, 0);
    __syncthreads();
  }

  #pragma unroll
  for (int j=0;j<NJ;j++){
    int n = bn + wn + 16*j + frow;
    float bv = bz ? bz[n] : 0.f;
    #pragma unroll
    for (int i=0;i<4;i++){
      int m0 = bm + wm + 16*i + kg*4;
      #pragma unroll
      for (int r=0;r<4;r++){
        int m = m0 + r;
        if (m < M){
          float v = acc[i][j][r] + bv;
          if (mode == 1) v = gelu_f(v);
          float* cp = &C[(size_t)m*ldC + n];
          if (mode == 2) v += *cp;
          *cp = v;
        }
      }
    }
  }
}

// ---------------- embedding + time features ----------------
__global__ __launch_bounds__(256) void k_embed(
  const int* __restrict__ ids, const int* __restrict__ ts, const int* __restrict__ lens,
  const float* __restrict__ item_emb, const float* __restrict__ pos_emb,
  const float* __restrict__ gap_emb, const float* __restrict__ rec_emb,
  const float* __restrict__ tf_w1, const float* __restrict__ tf_b1,
  float* __restrict__ xbuf, float* __restrict__ tfh)
{
  int bt = blockIdx.x;
  int b = bt / T_, t = bt % T_;
  int d = threadIdx.x;
  int len = lens[b];
  int tcur = ts[b*T_+t];
  int tlast = ts[b*T_+T_-1];
  bool mask  = t >= T_ - len;
  bool pmask = (t >= 1) && ((t-1) >= T_ - len);
  int gap = 0;
  if (mask && pmask){ int pv = ts[b*T_+t-1]; gap = max(tcur - pv, 0); }
  int rec = mask ? max(tlast - tcur, 0) : 0;
  int gb = min(max((int)floorf(log2f((float)gap + 1.0f)), 0), NB_-1);
  int rb = min(max((int)floorf(log2f((float)rec + 1.0f)), 0), NB_-1);
  float rec_raw = (float)max(tlast - tcur, 0);
  float tf0 = log1pf((float)gb);
  float tf1 = log1pf(rec_raw);
  float hid = gelu_f(tf0*tf_w1[d] + tf1*tf_w1[D_+d] + tf_b1[d]);
  tfh[(size_t)bt*D_ + d] = hid;
  int id = ids[b*T_+t];
  xbuf[(size_t)bt*D_ + d] = item_emb[(size_t)id*D_ + d] + pos_emb[t*D_ + d]
                          + gap_emb[gb*D_ + d] + rec_emb[rb*D_ + d];
}

// ---------------- LayerNorm (wave per row) ----------------
template<int NC>
__global__ __launch_bounds__(256) void k_ln(
  const float* __restrict__ in, float* __restrict__ out,
  const float* __restrict__ g, const float* __restrict__ bb,
  int rows, const int* __restrict__ lens, int applyMask)
{
  int wid = threadIdx.x >> 6, lane = threadIdx.x & 63;
  int r = blockIdx.x*4 + wid;
  if (r >= rows) return;
  const int D = NC*256;
  const float4* rp = (const float4*)(in + (size_t)r*D);
  float4 v[NC];
  float s = 0.f;
  #pragma unroll
  for (int c=0;c<NC;c++){ v[c] = rp[c*64 + lane]; s += v[c].x+v[c].y+v[c].z+v[c].w; }
  s = wsum(s);
  float mean = s / (float)D;
  float q = 0.f;
  #pragma unroll
  for (int c=0;c<NC;c++){
    float a=v[c].x-mean, b2=v[c].y-mean, c2=v[c].z-mean, d2=v[c].w-mean;
    q += a*a + b2*b2 + c2*c2 + d2*d2;
  }
  q = wsum(q);
  float rstd = rsqrtf(q/(float)D + 1e-5f);
  float m = 1.f;
  if (applyMask){ int t = r % T_; int b = r / T_; m = (t >= T_ - lens[b]) ? 1.f : 0.f; }
  float4* op = (float4*)(out + (size_t)r*D);
  #pragma unroll
  for (int c=0;c<NC;c++){
    float4 gg  = ((const float4*)g )[c*64+lane];
    float4 bv  = ((const float4*)bb)[c*64+lane];
    float4 o;
    o.x = ((v[c].x-mean)*rstd*gg.x + bv.x)*m;
    o.y = ((v[c].y-mean)*rstd*gg.y + bv.y)*m;
    o.z = ((v[c].z-mean)*rstd*gg.z + bv.z)*m;
    o.w = ((v[c].w-mean)*rstd*gg.w + bv.w)*m;
    op[c*64+lane] = o;
  }
}

// ---------------- causal linear attention (writes into cat640[...,0:128]) ----------------
#define CH_ 25
__global__ __launch_bounds__(64) void k_attn(
  const float* __restrict__ proj, const int* __restrict__ lens, float* __restrict__ cat)
{
  int bh = blockIdx.x; int b = bh >> 2, h = bh & 3;
  int lane = threadIdx.x; int e = lane & 31; int half = lane >> 5;
  int tstart = T_ - lens[b];
  __shared__ float sq[CH_*32], sk[CH_*32], sv[CH_*32];
  float kv[16]; float kp[16];
  #pragma unroll
  for (int j=0;j<16;j++){ kv[j]=0.f; kp[j]=0.f; }
  for (int c=0;c<T_/CH_;c++){
    int t0 = c*CH_;
    __syncthreads();
    for (int idx=lane; idx<CH_*32; idx+=64){
      int tl = idx >> 5, dd = idx & 31;
      int t = t0 + tl;
      float m = (t >= tstart) ? 1.f : 0.f;
      const float* pr = proj + (size_t)(b*T_+t)*640 + h*32 + dd;
      float qv = pr[256], kw = pr[384], vv = pr[512];
      qv = (qv > 0.f ? qv + 1.f : __expf(qv)) * m;
      kw = (kw > 0.f ? kw + 1.f : __expf(kw)) * m;
      sq[idx] = qv; sk[idx] = kw; sv[idx] = vv * m;
    }
    __syncthreads();
    for (int tl=0; tl<CH_; tl++){
      const float4* q4 = (const float4*)(sq + tl*32 + half*16);
      const float4* k4 = (const float4*)(sk + tl*32 + half*16);
      float vf = sv[tl*32 + e];
      float num=0.f, den=0.f, qk=0.f;
      #pragma unroll
      for (int jj=0;jj<4;jj++){
        float4 qq = q4[jj]; float4 kk = k4[jj];
        int j = jj*4;
        num += qq.x*kv[j] + qq.y*kv[j+1] + qq.z*kv[j+2] + qq.w*kv[j+3];
        den += qq.x*kp[j] + qq.y*kp[j+1] + qq.z*kp[j+2] + qq.w*kp[j+3];
        qk  += qq.x*kk.x + qq.y*kk.y + qq.z*kk.z + qq.w*kk.w;
        kv[j]   += kk.x*vf; kv[j+1] += kk.y*vf; kv[j+2] += kk.z*vf; kv[j+3] += kk.w*vf;
        kp[j]   += kk.x;    kp[j+1] += kk.y;    kp[j+2] += kk.z;    kp[j+3] += kk.w;
      }
      num += __shfl_xor(num,32,64);
      den += __shfl_xor(den,32,64);
      qk  += __shfl_xor(qk ,32,64);
      int t = t0 + tl;
      float m = (t >= tstart) ? 1.f : 0.f;
      num += qk * vf;
      den += qk;
      float o = num/(den + 1e-6f)*m;
      if (half == 0) cat[(size_t)(b*T_+t)*640 + h*32 + e] = o;
    }
  }
}

// ---------------- depthwise causal convs into cat640[...,128:640] ----------------
__global__ __launch_bounds__(256) void k_dwconv(
  const float* __restrict__ nrm, const float* __restrict__ tw, const float* __restrict__ tb,
  const float* __restrict__ pw, const float* __restrict__ pb, float* __restrict__ cat)
{
  int idx = blockIdx.x*256 + threadIdx.x;
  int d = idx & 255; int bt = idx >> 8; int t = bt % T_;
  float xs[5];
  #pragma unroll
  for (int j=0;j<5;j++){
    int tt = t - 4 + j;
    xs[j] = (tt >= 0) ? nrm[(size_t)(bt - 4 + j)*D_ + d] : 0.f;
  }
  float tmp = tw[d*3+0]*xs[2] + tw[d*3+1]*xs[3] + tw[d*3+2]*xs[4] + tb[d];
  float pos = pb[d];
  #pragma unroll
  for (int j=0;j<5;j++) pos += pw[d*5+j]*xs[j];
  cat[(size_t)bt*640 + 128 + d] = tmp;
  cat[(size_t)bt*640 + 384 + d] = pos;
}

// ---------------- fused: x=(x+sig(gate)*mixed)*mf ; h=LN2(x) ----------------
__global__ __launch_bounds__(256) void k_postmix_ln(
  float* __restrict__ x, const float* __restrict__ proj, const float* __restrict__ mixed,
  const int* __restrict__ lens, const float* __restrict__ g, const float* __restrict__ bb,
  float* __restrict__ h)
{
  int wid = threadIdx.x >> 6, lane = threadIdx.x & 63;
  int r = blockIdx.x*4 + wid;
  int t = r % T_, b = r / T_;
  float m = (t >= T_ - lens[b]) ? 1.f : 0.f;
  float4 xv = ((const float4*)(x     + (size_t)r*256))[lane];
  float4 gv = ((const float4*)(proj  + (size_t)r*640))[lane];
  float4 mx = ((const float4*)(mixed + (size_t)r*256))[lane];
  float4 xn;
  xn.x = (xv.x + mx.x/(1.f+__expf(-gv.x)))*m;
  xn.y = (xv.y + mx.y/(1.f+__expf(-gv.y)))*m;
  xn.z = (xv.z + mx.z/(1.f+__expf(-gv.z)))*m;
  xn.w = (xv.w + mx.w/(1.f+__expf(-gv.w)))*m;
  float s = wsum(xn.x+xn.y+xn.z+xn.w);
  float mean = s/256.f;
  float a=xn.x-mean, b2=xn.y-mean, c2=xn.z-mean, d2=xn.w-mean;
  float q = wsum(a*a+b2*b2+c2*c2+d2*d2);
  float rstd = rsqrtf(q/256.f + 1e-5f);
  ((float4*)(x + (size_t)r*256))[lane] = xn;
  float4 gg = ((const float4*)g )[lane];
  float4 bv = ((const float4*)bb)[lane];
  float4 o;
  o.x = a*rstd*gg.x + bv.x;
  o.y = b2*rstd*gg.y + bv.y;
  o.z = c2*rstd*gg.z + bv.z;
  o.w = d2*rstd*gg.w + bv.w;
  ((float4*)(h + (size_t)r*256))[lane] = o;
}

// ---------------- fused: x=(x+f)*mf ; nrm = LN(x) [optionally masked for final] ----------------
__global__ __launch_bounds__(256) void k_addln(
  float* __restrict__ x, const float* __restrict__ f, const int* __restrict__ lens,
  const float* __restrict__ g, const float* __restrict__ bb,
  float* __restrict__ nrm, int maskLN)
{
  int wid = threadIdx.x >> 6, lane = threadIdx.x & 63;
  int r = blockIdx.x*4 + wid;
  int t = r % T_, b = r / T_;
  float m = (t >= T_ - lens[b]) ? 1.f : 0.f;
  float4 xv = ((const float4*)(x + (size_t)r*256))[lane];
  float4 fv = ((const float4*)(f + (size_t)r*256))[lane];
  float4 xn;
  xn.x = (xv.x + fv.x)*m;
  xn.y = (xv.y + fv.y)*m;
  xn.z = (xv.z + fv.z)*m;
  xn.w = (xv.w + fv.w)*m;
  float s = wsum(xn.x+xn.y+xn.z+xn.w);
  float mean = s/256.f;
  float a=xn.x-mean, b2=xn.y-mean, c2=xn.z-mean, d2=xn.w-mean;
  float q = wsum(a*a+b2*b2+c2*c2+d2*d2);
  float rstd = rsqrtf(q/256.f + 1e-5f);
  ((float4*)(x + (size_t)r*256))[lane] = xn;
  float ml = maskLN ? m : 1.f;
  float4 gg = ((const float4*)g )[lane];
  float4 bv = ((const float4*)bb)[lane];
  float4 o;
  o.x = (a*rstd*gg.x + bv.x)*ml;
  o.y = (b2*rstd*gg.y + bv.y)*ml;
  o.z = (c2*rstd*gg.z + bv.z)*ml;
  o.w = (d2*rstd*gg.w + bv.w)*ml;
  ((float4*)(nrm + (size_t)r*256))[lane] = o;
}

// ---------------- pooling ----------------
__global__ __launch_bounds__(256) void k_pool(
  const float* __restrict__ x, const int* __restrict__ lens,
  const float* __restrict__ pg_w, const float* __restrict__ pg_b,
  float* __restrict__ u0)
{
  int b = blockIdx.x;
  int tid = threadIdx.x, wid = tid>>6, lane = tid&63;
  __shared__ float sps[T_];
  __shared__ float spw[T_];
  int len = lens[b]; int tstart = T_ - len;
  const float4* pw4 = (const float4*)pg_w;
  float4 wv = pw4[lane];
  for (int t = wid; t < T_; t += 4){
    const float4* xr = (const float4*)(x + (size_t)(b*T_+t)*D_);
    float4 xv = xr[lane];
    float dot = xv.x*wv.x + xv.y*wv.y + xv.z*wv.z + xv.w*wv.w;
    dot = wsum(dot);
    if (lane==0) sps[t] = (t >= tstart) ? dot + pg_b[0] : -1e9f;
  }
  __syncthreads();
  float mx = -1e30f;
  for (int t=0;t<T_;t++) mx = fmaxf(mx, sps[t]);
  float sum = 0.f;
  for (int t=0;t<T_;t++) sum += __expf(sps[t]-mx);
  float inv = 1.f/sum;
  if (tid < T_) spw[tid] = __expf(sps[tid]-mx)*inv;
  __syncthreads();
  int d = tid;
  float macc=0.f, aacc=0.f;
  for (int t=0;t<T_;t++){
    float v = x[(size_t)(b*T_+t)*D_ + d];
    macc += v;
    aacc += spw[t]*v;
  }
  u0[b*768 + d]       = x[(size_t)(b*T_+T_-1)*D_ + d];
  u0[b*768 + 256 + d] = macc / (float)max(len,1);
  u0[b*768 + 512 + d] = aacc;
}

// ---------------- normalize u rows + emit bf16 ----------------
__global__ __launch_bounds__(64) void k_norm(float* __restrict__ u, unsigned short* __restrict__ ub)
{
  int b = blockIdx.x; int lane = threadIdx.x;
  float4* r = (float4*)(u + b*256);
  float4 v = r[lane];
  float ss = v.x*v.x + v.y*v.y + v.z*v.z + v.w*v.w;
  ss = wsum(ss);
  float sc = 1.f/fmaxf(sqrtf(ss), 1e-12f);
  v.x*=sc; v.y*=sc; v.z*=sc; v.w*=sc;
  r[lane]=v;
  ub[b*256 + lane*4 + 0] = f2bf(v.x);
  ub[b*256 + lane*4 + 1] = f2bf(v.y);
  ub[b*256 + lane*4 + 2] = f2bf(v.z);
  ub[b*256 + lane*4 + 3] = f2bf(v.w);
}

// ---------------- scoring via MFMA: 128 items x 32 users per block ----------------
__global__ __launch_bounds__(256) void k_score_mfma(
  const float* __restrict__ item_emb, const unsigned short* __restrict__ ub,
  const float* __restrict__ item_bias, float* __restrict__ out)
{
  __shared__ unsigned short Als[128][40];
  __shared__ unsigned short Bls[32][264];
  __shared__ float ssA[128][2];
  int tid = threadIdx.x;
  int wave = tid >> 6, lane = tid & 63;
  int frow = lane & 15, kg = lane >> 4;
  int wm = wave * 32;
  int n0 = blockIdx.x * 128;
  // load all of u (32 x 256 bf16)
  for (int i = tid; i < 32*32; i += 256){
    int rr = i >> 5, c = i & 31;
    *(ushort8*)&Bls[rr][c*8] = *(const ushort8*)&ub[rr*256 + c*8];
  }
  int sm = tid >> 1, skh = (tid & 1) * 16;
  float ssreg = 0.f;
  floatx4 acc[2][2];
  #pragma unroll
  for (int i=0;i<2;i++)
    #pragma unroll
    for (int j=0;j<2;j++) acc[i][j] = (floatx4){0.f,0.f,0.f,0.f};

  for (int k0=0; k0<256; k0+=32){
    int gn = n0 + sm;
    float f[16];
    if (gn < NI_){
      const float4* ap = (const float4*)(item_emb + (size_t)(gn+1)*256 + k0 + skh);
      #pragma unroll
      for (int c=0;c<4;c++){ float4 v = ap[c]; f[c*4]=v.x; f[c*4+1]=v.y; f[c*4+2]=v.z; f[c*4+3]=v.w; }
    } else {
      #pragma unroll
      for (int c=0;c<16;c++) f[c]=0.f;
    }
    ushort8 pa, pb;
    #pragma unroll
    for (int c=0;c<8;c++){
      ssreg += f[c]*f[c] + f[8+c]*f[8+c];
      pa[c]=f2bf(f[c]); pb[c]=f2bf(f[8+c]);
    }
    *(ushort8*)&Als[sm][skh]   = pa;
    *(ushort8*)&Als[sm][skh+8] = pb;
    __syncthreads();
    short8 af[2], bf[2];
    #pragma unroll
    for (int i=0;i<2;i++) af[i] = *(const short8*)&Als[wm + 16*i + frow][kg*8];
    #pragma unroll
    for (int j=0;j<2;j++) bf[j] = *(const short8*)&Bls[16*j + frow][k0 + kg*8];
    #pragma unroll
    for (int i=0;i<2;i++)
      #pragma unroll
      for (int j=0;j<2;j++)
        acc[i][j] = __builtin_amdgcn_mfma_f32_16x16x32_bf16(af[i], bf[j], acc[i][j], 0, 0, 0);
    __syncthreads();
  }
  ssA[sm][tid&1] = ssreg;
  __syncthreads();
  #pragma unroll
  for (int i=0;i<2;i++){
    #pragma unroll
    for (int r=0;r<4;r++){
      int ml = wm + 16*i + kg*4 + r;
      int n = n0 + ml;
      if (n < NI_){
        float ss = ssA[ml][0] + ssA[ml][1];
        float sc = 1.f/fmaxf(sqrtf(ss), 1e-12f);
        float bias = item_bias[n+1];
        #pragma unroll
        for (int j=0;j<2;j++){
          int bcol = 16*j + frow;
          out[(size_t)bcol*NI_ + n] = acc[i][j][r]*sc + bias;
        }
      }
    }
  }
}

extern "C" void kernel_launch(void* const* d_in, const int* in_sizes, int n_in,
                              void* d_out, int out_size, void* d_ws, size_t ws_size,
                              hipStream_t stream)
{
  const int* ids  = (const int*)d_in[0];
  const int* ts   = (const int*)d_in[1];
  const int* lens = (const int*)d_in[2];
  const float* item_emb = (const float*)d_in[3];
  const float* pos_emb  = (const float*)d_in[4];
  const float* gap_emb  = (const float*)d_in[5];
  const float* rec_emb  = (const float*)d_in[6];
  const float* tf_w1 = (const float*)d_in[7];
  const float* tf_b1 = (const float*)d_in[8];
  const float* tf_w2 = (const float*)d_in[9];
  const float* tf_b2 = (const float*)d_in[10];
  const float* in_g  = (const float*)d_in[11];
  const float* in_b  = (const float*)d_in[12];
  const float* l_ln1g = (const float*)d_in[13];
  const float* l_ln1b = (const float*)d_in[14];
  const float* l_win  = (const float*)d_in[15];
  const float* l_bin  = (const float*)d_in[16];
  const float* l_wc   = (const float*)d_in[17];
  const float* l_bc   = (const float*)d_in[18];
  const float* l_tw   = (const float*)d_in[19];
  const float* l_tb   = (const float*)d_in[20];
  const float* l_pw   = (const float*)d_in[21];
  const float* l_pb   = (const float*)d_in[22];
  const float* l_wmix = (const float*)d_in[23];
  const float* l_bmix = (const float*)d_in[24];
  const float* l_ln2g = (const float*)d_in[25];
  const float* l_ln2b = (const float*)d_in[26];
  const float* l_wf1  = (const float*)d_in[27];
  const float* l_bf1  = (const float*)d_in[28];
  const float* l_wf2  = (const float*)d_in[29];
  const float* l_bf2  = (const float*)d_in[30];
  const float* fn_g = (const float*)d_in[31];
  const float* fn_b = (const float*)d_in[32];
  const float* pg_w = (const float*)d_in[33];
  const float* pg_b = (const float*)d_in[34];
  const float* uh_w1 = (const float*)d_in[35];
  const float* uh_b1 = (const float*)d_in[36];
  const float* uh_lng = (const float*)d_in[37];
  const float* uh_lnb = (const float*)d_in[38];
  const float* uh_w2 = (const float*)d_in[39];
  const float* uh_b2 = (const float*)d_in[40];
  const float* item_bias = (const float*)d_in[41];
  float* out = (float*)d_out;

  const int MT = B_*T_;
  float* ws   = (float*)d_ws;
  float* xbuf = ws;                               // 1,638,400
  float* tmp  = xbuf + (size_t)MT*D_;             // 1,638,400 (nrm / h)
  float* proj = tmp  + (size_t)MT*D_;             // 4,096,000 (also ffn2 out)
  float* cat  = proj + (size_t)MT*640;            // 4,096,000 (640-wide)
  float* mid  = cat  + (size_t)MT*640;            // 6,553,600 (mixed 256 / ffn1 1024)
  float* u0   = mid  + (size_t)MT*FF_;            // 24,576
  float* u1   = u0 + 32*768;                      // 32,768
  float* u2   = u1 + 32*1024;                     // 8,192
  float* WcombF = u2 + 32*256;                    // 262,144 (8 x 128 x 256)
  float* bmixP  = WcombF + 262144;                // 2,048
  unsigned short* WtPerm = (unsigned short*)(bmixP + 2048);  // 5,505,024 ush
  unsigned short* WtMixT = WtPerm + 5505024;      // 1,572,864 ush
  unsigned short* WtBig  = WtMixT + 1572864;      // 1,310,720 ush
  unsigned short* WtH    = WtBig  + 1310720;      // 1,114,112 ush
  unsigned short* u2b    = WtH    + 1114112;      // 8,192 ush

  // ---- weight prep (one-time per launch) ----
  k_cvtAll<<<8000, 256, 0, stream>>>(l_win, l_wmix, l_wf1, l_wf2, tf_w2, uh_w1, uh_w2,
                                     WtPerm, WtMixT, WtH);
  // WcombF[l] = wc_l (128x256 fp32) @ wmix_c_l  (Wt = wmixT rows, ldW=768)
  k_gemm_bf<64><<<dim3(4,1,8), 256, 0, stream>>>(l_wc, WtMixT, nullptr, WcombF,
                                                 128, 256, 256, 256, 768, 256, 0,
                                                 (size_t)128*256, (size_t)196608, (size_t)32768, 0);
  k_asm<<<64, 256, 0, stream>>>(WcombF, WtMixT, WtBig);
  k_bfold<<<8, 256, 0, stream>>>(l_bc, l_bmix, l_wmix, bmixP);

  // ---- embedding + dense time ----
  k_embed<<<MT, 256, 0, stream>>>(ids, ts, lens, item_emb, pos_emb, gap_emb, rec_emb,
                                  tf_w1, tf_b1, xbuf, tmp);
  k_gemm_bf<64><<<dim3(4,50), 256, 0, stream>>>(tmp, WtH, tf_b2, xbuf,
                                                MT, 256, 256, 256, 256, 256, 2, 0,0,0,0);
  k_ln<1><<<MT/4, 256, 0, stream>>>(xbuf, xbuf, in_g, in_b, MT, lens, 1);
  k_ln<1><<<MT/4, 256, 0, stream>>>(xbuf, tmp, l_ln1g, l_ln1b, MT, lens, 0);

  // ---- layers ----
  for (int i=0;i<L_;i++){
    const unsigned short* WL = WtPerm + (size_t)i*688128;
    k_gemm_bf<128><<<dim3(5,50), 256, 0, stream>>>(tmp, WL, l_bin+i*640, proj,
                                                   MT, 640, 256, 256, 256, 640, 0, 0,0,0,0);
    k_attn<<<B_*H_, 64, 0, stream>>>(proj, lens, cat);
    k_dwconv<<<MT, 256, 0, stream>>>(tmp, l_tw+i*768, l_tb+i*256, l_pw+i*1280, l_pb+i*256, cat);
    k_gemm_bf<64><<<dim3(4,50), 256, 0, stream>>>(cat, WtBig+(size_t)i*163840, bmixP+i*256, mid,
                                                  MT, 256, 640, 640, 640, 256, 0, 0,0,0,0);
    k_postmix_ln<<<MT/4, 256, 0, stream>>>(xbuf, proj, mid, lens, l_ln2g+i*256, l_ln2b+i*256, tmp);
    k_gemm_bf<128><<<dim3(8,50), 256, 0, stream>>>(tmp, WL+163840, l_bf1+i*FF_, mid,
                                                   MT, FF_, 256, 256, 256, FF_, 1, 0,0,0,0);
    k_gemm_bf<64><<<dim3(4,50), 256, 0, stream>>>(mid, WL+425984, l_bf2+i*256, proj,
                                                  MT, 256, 1024, 1024, 1024, 256, 0, 0,0,0,0);
    bool last = (i == L_-1);
    k_addln<<<MT/4, 256, 0, stream>>>(xbuf, proj, lens,
                                      last ? fn_g : l_ln1g+(i+1)*256,
                                      last ? fn_b : l_ln1b+(i+1)*256,
                                      tmp, last ? 1 : 0);
  }

  // ---- pooling + user head (final LN'd x is in tmp) ----
  k_pool<<<B_, 256, 0, stream>>>(tmp, lens, pg_w, pg_b, u0);
  k_gemm_bf<128><<<dim3(8,1), 256, 0, stream>>>(u0, WtH+65536, uh_b1, u1,
                                                32, 1024, 768, 768, 768, 1024, 1, 0,0,0,0);
  k_ln<4><<<8, 256, 0, stream>>>(u1, u1, uh_lng, uh_lnb, 32, lens, 0);
  k_gemm_bf<64><<<dim3(4,1), 256, 0, stream>>>(u1, WtH+851968, uh_b2, u2,
                                               32, 256, 1024, 1024, 1024, 256, 0, 0,0,0,0);
  k_norm<<<B_, 64, 0, stream>>>(u2, u2b);

  // ---- scoring ----
  k_score_mfma<<<(NI_+127)/128, 256, 0, stream>>>(item_emb, u2b, item_bias, out);
}

// Round 5
// 2080.960 us; speedup vs baseline: 2.9943x; 1.1634x over previous
//
#include <hip/hip_runtime.h>
#include <math.h>

#define B_ 32
#define T_ 200
#define D_ 256
#define H_ 4
#define DH_ 32
#define INNER_ 128
#define L_ 8
#define FF_ 1024
#define NI_ 100000
#define NB_ 64
#define CH_ 25

typedef __attribute__((ext_vector_type(8))) short short8;
typedef __attribute__((ext_vector_type(8))) unsigned short ushort8;
typedef __attribute__((ext_vector_type(4))) float floatx4;

__device__ __forceinline__ float gelu_f(float x){
  return 0.5f*x*(1.0f+erff(x*0.70710678118654752f));
}
__device__ __forceinline__ float wsum(float v){
  #pragma unroll
  for (int o=32;o>0;o>>=1) v += __shfl_xor(v,o,64);
  return v;
}
__device__ __forceinline__ unsigned short f2bf(float x){
  unsigned int u = __float_as_uint(x);
  unsigned int r = (u + 0x7fffu + ((u>>16)&1u)) >> 16;
  return (unsigned short)r;
}

// ---------------- weight fp32 [K][N] -> bf16 W^T [N][K] tile transpose ----------------
__device__ __forceinline__ void cvt_tile(const float* __restrict__ src, unsigned short* __restrict__ dst,
                                         int K, int N, int tk, int tn, int tid, float (*s)[33])
{
  int tx = tid & 31, ty0 = tid >> 5;
  #pragma unroll
  for (int it=0; it<4; ++it){
    int ty = ty0 + it*8;
    s[ty][tx] = src[(size_t)(tk*32+ty)*N + tn*32+tx];
  }
  __syncthreads();
  #pragma unroll
  for (int it=0; it<4; ++it){
    int ty = ty0 + it*8;
    dst[(size_t)(tn*32+ty)*K + tk*32 + tx] = f2bf(s[tx][ty]);
  }
}

// ALL weight conversions in one dispatch.
__global__ __launch_bounds__(256) void k_cvtAll(
  const float* __restrict__ win, const float* __restrict__ wmix,
  const float* __restrict__ wf1, const float* __restrict__ wf2,
  const float* __restrict__ tfw2, const float* __restrict__ uhw1, const float* __restrict__ uhw2,
  unsigned short* __restrict__ WtPerm, unsigned short* __restrict__ WtMixT,
  unsigned short* __restrict__ WtH)
{
  __shared__ float s[32][33];
  int b = blockIdx.x, tid = threadIdx.x;
  if (b < 6912){
    int l = b / 864, r = b % 864;
    if (r < 160)      cvt_tile(win + (size_t)l*163840, WtPerm + (size_t)l*688128,          256, 640,  r/20,      r%20,      tid, s);
    else if (r < 352){int t=r-160; cvt_tile(wmix + (size_t)l*196608, WtMixT + (size_t)l*196608, 768, 256, t/8, t%8, tid, s);}
    else if (r < 608){int t=r-352; cvt_tile(wf1 + (size_t)l*262144, WtPerm + (size_t)l*688128 + 163840, 256, 1024, t/32, t%32, tid, s);}
    else             {int t=r-608; cvt_tile(wf2 + (size_t)l*262144, WtPerm + (size_t)l*688128 + 425984, 1024, 256, t/8, t%8, tid, s);}
  } else {
    int r = b - 6912;
    if (r < 64)       cvt_tile(tfw2, WtH,        256, 256,  r/8,  r%8,  tid, s);
    else if (r < 832){int t=r-64;  cvt_tile(uhw1, WtH+65536,  768, 1024, t/32, t%32, tid, s);}
    else             {int t=r-832; cvt_tile(uhw2, WtH+851968, 1024, 256, t/8,  t%8,  tid, s);}
  }
}

// assemble WtBig[l][256 n][640 k]: k<128 from WcombF^T, k>=128 copy wmixT (d=k+128)
__global__ __launch_bounds__(256) void k_asm(
  const float* __restrict__ WcombF, const unsigned short* __restrict__ WtMixT,
  unsigned short* __restrict__ WtBig)
{
  int l = blockIdx.x >> 3, g = blockIdx.x & 7;
  int tid = threadIdx.x;
  int n = g*32 + (tid >> 3);
  int k0 = (tid & 7) * 80;
  const float* wc = WcombF + (size_t)l*32768;
  const unsigned short* wm = WtMixT + (size_t)l*196608 + (size_t)n*768;
  unsigned short* dst = WtBig + (size_t)l*163840 + (size_t)n*640;
  for (int kk=0; kk<80; kk++){
    int k = k0 + kk;
    dst[k] = (k < 128) ? f2bf(wc[(size_t)k*256 + n]) : wm[k+128];
  }
}

// bmixP[l][n] = bmix[l][n] + sum_d bc[l][d] * wmix[l][d][n]
__global__ __launch_bounds__(256) void k_bfold(
  const float* __restrict__ bc, const float* __restrict__ bmix,
  const float* __restrict__ wmix, float* __restrict__ bmixP)
{
  int l = blockIdx.x; int n = threadIdx.x;
  const float* w = wmix + (size_t)l*196608;
  const float* c = bc + l*256;
  float s = bmix[l*256 + n];
  for (int d=0; d<256; d++) s += c[d]*w[(size_t)d*256 + n];
  bmixP[l*256+n] = s;
}

// ---------------- bf16 MFMA GEMM ----------------
template<int TN>
__global__ __launch_bounds__(256) void k_gemm_bf(
    const float* __restrict__ A, const unsigned short* __restrict__ Wt,
    const float* __restrict__ bias, float* __restrict__ C,
    int M, int N, int K, int ldA, int ldW, int ldC, int mode,
    size_t sA, size_t sW, size_t sC, size_t sB)
{
  constexpr int NJ = TN/32;
  __shared__ unsigned short Als[128][40];
  __shared__ unsigned short Bls[TN][40];
  int z = blockIdx.z;
  A += (size_t)z*sA; Wt += (size_t)z*sW; C += (size_t)z*sC;
  const float* bz = bias ? bias + (size_t)z*sB : nullptr;
  int tid = threadIdx.x;
  int wave = tid >> 6, lane = tid & 63;
  int wm = (wave >> 1) * 64, wn = (wave & 1) * (TN/2);
  int frow = lane & 15, kg = lane >> 4;
  int bm = blockIdx.y * 128, bn = blockIdx.x * TN;
  int sm = tid >> 1, skh = (tid & 1) * 16;

  floatx4 acc[4][NJ];
  #pragma unroll
  for (int i=0;i<4;i++)
    #pragma unroll
    for (int j=0;j<NJ;j++) acc[i][j] = (floatx4){0.f,0.f,0.f,0.f};

  for (int k0=0; k0<K; k0+=32){
    {
      int gm = bm + sm;
      float f[16];
      if (gm < M){
        const float4* ap = (const float4*)(A + (size_t)gm*ldA + k0 + skh);
        #pragma unroll
        for (int c=0;c<4;c++){ float4 v = ap[c]; f[c*4]=v.x; f[c*4+1]=v.y; f[c*4+2]=v.z; f[c*4+3]=v.w; }
      } else {
        #pragma unroll
        for (int c=0;c<16;c++) f[c]=0.f;
      }
      ushort8 pa, pb;
      #pragma unroll
      for (int c=0;c<8;c++){ pa[c]=f2bf(f[c]); pb[c]=f2bf(f[8+c]); }
      *(ushort8*)&Als[sm][skh]   = pa;
      *(ushort8*)&Als[sm][skh+8] = pb;
    }
    #pragma unroll
    for (int u=0; u<TN/64; u++){
      int li = tid + u*256;
      int row = li >> 2, koff = (li & 3) * 8;
      int gn = bn + row;
      ushort8 wv;
      if (gn < N){
        wv = *(const ushort8*)&Wt[(size_t)gn*ldW + k0 + koff];
      } else {
        for (int c=0;c<8;c++) wv[c]=0;
      }
      *(ushort8*)&Bls[row][koff] = wv;
    }
    __syncthreads();
    short8 af[4], bf[NJ];
    #pragma unroll
    for (int i=0;i<4;i++) af[i] = *(const short8*)&Als[wm + 16*i + frow][kg*8];
    #pragma unroll
    for (int j=0;j<NJ;j++) bf[j] = *(const short8*)&Bls[wn + 16*j + frow][kg*8];
    #pragma unroll
    for (int i=0;i<4;i++)
      #pragma unroll
      for (int j=0;j<NJ;j++)
        acc[i][j] = __builtin_amdgcn_mfma_f32_16x16x32_bf16(af[i], bf[j], acc[i][j], 0, 0, 0);
    __syncthreads();
  }

  #pragma unroll
  for (int j=0;j<NJ;j++){
    int n = bn + wn + 16*j + frow;
    float bv = bz ? bz[n] : 0.f;
    #pragma unroll
    for (int i=0;i<4;i++){
      int m0 = bm + wm + 16*i + kg*4;
      #pragma unroll
      for (int r=0;r<4;r++){
        int m = m0 + r;
        if (m < M){
          float v = acc[i][j][r] + bv;
          if (mode == 1) v = gelu_f(v);
          float* cp = &C[(size_t)m*ldC + n];
          if (mode == 2) v += *cp;
          *cp = v;
        }
      }
    }
  }
}

// ---------------- embedding + time features ----------------
__global__ __launch_bounds__(256) void k_embed(
  const int* __restrict__ ids, const int* __restrict__ ts, const int* __restrict__ lens,
  const float* __restrict__ item_emb, const float* __restrict__ pos_emb,
  const float* __restrict__ gap_emb, const float* __restrict__ rec_emb,
  const float* __restrict__ tf_w1, const float* __restrict__ tf_b1,
  float* __restrict__ xbuf, float* __restrict__ tfh)
{
  int bt = blockIdx.x;
  int b = bt / T_, t = bt % T_;
  int d = threadIdx.x;
  int len = lens[b];
  int tcur = ts[b*T_+t];
  int tlast = ts[b*T_+T_-1];
  bool mask  = t >= T_ - len;
  bool pmask = (t >= 1) && ((t-1) >= T_ - len);
  int gap = 0;
  if (mask && pmask){ int pv = ts[b*T_+t-1]; gap = max(tcur - pv, 0); }
  int rec = mask ? max(tlast - tcur, 0) : 0;
  int gb = min(max((int)floorf(log2f((float)gap + 1.0f)), 0), NB_-1);
  int rb = min(max((int)floorf(log2f((float)rec + 1.0f)), 0), NB_-1);
  float rec_raw = (float)max(tlast - tcur, 0);
  float tf0 = log1pf((float)gb);
  float tf1 = log1pf(rec_raw);
  float hid = gelu_f(tf0*tf_w1[d] + tf1*tf_w1[D_+d] + tf_b1[d]);
  tfh[(size_t)bt*D_ + d] = hid;
  int id = ids[b*T_+t];
  xbuf[(size_t)bt*D_ + d] = item_emb[(size_t)id*D_ + d] + pos_emb[t*D_ + d]
                          + gap_emb[gb*D_ + d] + rec_emb[rb*D_ + d];
}

// ---------------- LayerNorm (wave per row) ----------------
template<int NC>
__global__ __launch_bounds__(256) void k_ln(
  const float* __restrict__ in, float* __restrict__ out,
  const float* __restrict__ g, const float* __restrict__ bb,
  int rows, const int* __restrict__ lens, int applyMask)
{
  int wid = threadIdx.x >> 6, lane = threadIdx.x & 63;
  int r = blockIdx.x*4 + wid;
  if (r >= rows) return;
  const int D = NC*256;
  const float4* rp = (const float4*)(in + (size_t)r*D);
  float4 v[NC];
  float s = 0.f;
  #pragma unroll
  for (int c=0;c<NC;c++){ v[c] = rp[c*64 + lane]; s += v[c].x+v[c].y+v[c].z+v[c].w; }
  s = wsum(s);
  float mean = s / (float)D;
  float q = 0.f;
  #pragma unroll
  for (int c=0;c<NC;c++){
    float a=v[c].x-mean, b2=v[c].y-mean, c2=v[c].z-mean, d2=v[c].w-mean;
    q += a*a + b2*b2 + c2*c2 + d2*d2;
  }
  q = wsum(q);
  float rstd = rsqrtf(q/(float)D + 1e-5f);
  float m = 1.f;
  if (applyMask){ int t = r % T_; int b = r / T_; m = (t >= T_ - lens[b]) ? 1.f : 0.f; }
  float4* op = (float4*)(out + (size_t)r*D);
  #pragma unroll
  for (int c=0;c<NC;c++){
    float4 gg  = ((const float4*)g )[c*64+lane];
    float4 bv  = ((const float4*)bb)[c*64+lane];
    float4 o;
    o.x = ((v[c].x-mean)*rstd*gg.x + bv.x)*m;
    o.y = ((v[c].y-mean)*rstd*gg.y + bv.y)*m;
    o.z = ((v[c].z-mean)*rstd*gg.z + bv.z)*m;
    o.w = ((v[c].w-mean)*rstd*gg.w + bv.w)*m;
    op[c*64+lane] = o;
  }
}

// ---------------- chunked linear attention, phase A: per-chunk sums ----------------
// grid: (b,h,c) = 1024 blocks x 64 thr. Ssum[bh][c][1056] = {kv[d][e] d*32+e, ksum[32]}
__global__ __launch_bounds__(64) void k_attn_sums(
  const float* __restrict__ proj, const int* __restrict__ lens, float* __restrict__ Ssum)
{
  int blk = blockIdx.x;
  int bh = blk >> 3, c = blk & 7;
  int b = bh >> 2, h = bh & 3;
  int lane = threadIdx.x; int e = lane & 31, half = lane >> 5;
  int tstart = T_ - lens[b];
  __shared__ float sk[CH_*32], sv[CH_*32];
  int t0 = c*CH_;
  for (int idx = lane; idx < CH_*32; idx += 64){
    int tl = idx >> 5, dd = idx & 31;
    int t = t0 + tl;
    float m = (t >= tstart) ? 1.f : 0.f;
    const float* pr = proj + (size_t)(b*T_+t)*640 + h*32 + dd;
    float kw = pr[384], vv = pr[512];
    sk[idx] = (kw > 0.f ? kw + 1.f : __expf(kw)) * m;
    sv[idx] = vv * m;
  }
  __syncthreads();
  float acc[16];
  #pragma unroll
  for (int j=0;j<16;j++) acc[j]=0.f;
  for (int tl=0; tl<CH_; tl++){
    const float4* k4 = (const float4*)(sk + tl*32 + half*16);
    float vf = sv[tl*32 + e];
    #pragma unroll
    for (int jj=0;jj<4;jj++){
      float4 kk = k4[jj];
      acc[jj*4+0] += kk.x*vf;
      acc[jj*4+1] += kk.y*vf;
      acc[jj*4+2] += kk.z*vf;
      acc[jj*4+3] += kk.w*vf;
    }
  }
  float* dst = Ssum + ((size_t)bh*8 + c)*1056;
  #pragma unroll
  for (int j=0;j<16;j++) dst[(half*16+j)*32 + e] = acc[j];
  if (half == 0){
    float s = 0.f;
    for (int tl=0; tl<CH_; tl++) s += sk[tl*32 + e];
    dst[1024 + e] = s;
  }
}

// ---------------- phase C: per-chunk outputs (prefix built from prior chunk sums) ----------------
__global__ __launch_bounds__(64) void k_attn_out(
  const float* __restrict__ proj, const int* __restrict__ lens,
  const float* __restrict__ Ssum, float* __restrict__ cat)
{
  int blk = blockIdx.x;
  int bh = blk >> 3, c = blk & 7;
  int b = bh >> 2, h = bh & 3;
  int lane = threadIdx.x; int e = lane & 31, half = lane >> 5;
  int tstart = T_ - lens[b];
  __shared__ float sq[CH_*32], sk[CH_*32], sv[CH_*32];
  __shared__ float P[1056];
  __shared__ float A[CH_][CH_+1];
  __shared__ float sden[CH_];
  int t0 = c*CH_;
  const float* base = Ssum + (size_t)bh*8*1056;
  for (int idx = lane; idx < 1056; idx += 64){
    float s = 0.f;
    for (int cp=0; cp<c; cp++) s += base[cp*1056 + idx];
    P[idx] = s;
  }
  for (int idx = lane; idx < CH_*32; idx += 64){
    int tl = idx >> 5, dd = idx & 31;
    int t = t0 + tl;
    float m = (t >= tstart) ? 1.f : 0.f;
    const float* pr = proj + (size_t)(b*T_+t)*640 + h*32 + dd;
    float qv = pr[256], kw = pr[384], vv = pr[512];
    sq[idx] = (qv > 0.f ? qv + 1.f : __expf(qv)) * m;
    sk[idx] = (kw > 0.f ? kw + 1.f : __expf(kw)) * m;
    sv[idx] = vv * m;
  }
  __syncthreads();
  // A[t][tp] = q_t . k_tp  (tp <= t), else 0
  for (int idx = lane; idx < CH_*CH_; idx += 64){
    int t = idx / CH_, tp = idx - t*CH_;
    float s = 0.f;
    if (tp <= t){
      const float4* q4 = (const float4*)(sq + t*32);
      const float4* k4 = (const float4*)(sk + tp*32);
      #pragma unroll
      for (int jj=0;jj<8;jj++){
        float4 qq = q4[jj], kk = k4[jj];
        s += qq.x*kk.x + qq.y*kk.y + qq.z*kk.z + qq.w*kk.w;
      }
    }
    A[t][tp] = s;
  }
  __syncthreads();
  if (lane < CH_){
    int t = lane;
    float s = 0.f;
    for (int tp=0; tp<=t; tp++) s += A[t][tp];
    const float* qf = sq + t*32;
    #pragma unroll
    for (int d=0; d<32; d++) s += qf[d]*P[1024+d];
    sden[t] = s;
  }
  __syncthreads();
  int tlo = half ? 13 : 0;
  int thi = half ? CH_ : 13;
  for (int t = tlo; t < thi; t++){
    float num = 0.f;
    for (int tp=0; tp<=t; tp++) num += A[t][tp]*sv[tp*32+e];
    const float* qf = sq + t*32;
    #pragma unroll
    for (int d=0; d<32; d++) num += qf[d]*P[d*32+e];
    int tg = t0 + t;
    float m = (tg >= tstart) ? 1.f : 0.f;
    cat[(size_t)(b*T_+tg)*640 + h*32 + e] = num/(sden[t]+1e-6f)*m;
  }
}

// ---------------- depthwise causal convs into cat640[...,128:640] ----------------
__global__ __launch_bounds__(256) void k_dwconv(
  const float* __restrict__ nrm, const float* __restrict__ tw, const float* __restrict__ tb,
  const float* __restrict__ pw, const float* __restrict__ pb, float* __restrict__ cat)
{
  int idx = blockIdx.x*256 + threadIdx.x;
  int d = idx & 255; int bt = idx >> 8; int t = bt % T_;
  float xs[5];
  #pragma unroll
  for (int j=0;j<5;j++){
    int tt = t - 4 + j;
    xs[j] = (tt >= 0) ? nrm[(size_t)(bt - 4 + j)*D_ + d] : 0.f;
  }
  float tmp = tw[d*3+0]*xs[2] + tw[d*3+1]*xs[3] + tw[d*3+2]*xs[4] + tb[d];
  float pos = pb[d];
  #pragma unroll
  for (int j=0;j<5;j++) pos += pw[d*5+j]*xs[j];
  cat[(size_t)bt*640 + 128 + d] = tmp;
  cat[(size_t)bt*640 + 384 + d] = pos;
}

// ---------------- fused: x=(x+sig(gate)*mixed)*mf ; h=LN2(x) ----------------
__global__ __launch_bounds__(256) void k_postmix_ln(
  float* __restrict__ x, const float* __restrict__ proj, const float* __restrict__ mixed,
  const int* __restrict__ lens, const float* __restrict__ g, const float* __restrict__ bb,
  float* __restrict__ h)
{
  int wid = threadIdx.x >> 6, lane = threadIdx.x & 63;
  int r = blockIdx.x*4 + wid;
  int t = r % T_, b = r / T_;
  float m = (t >= T_ - lens[b]) ? 1.f : 0.f;
  float4 xv = ((const float4*)(x     + (size_t)r*256))[lane];
  float4 gv = ((const float4*)(proj  + (size_t)r*640))[lane];
  float4 mx = ((const float4*)(mixed + (size_t)r*256))[lane];
  float4 xn;
  xn.x = (xv.x + mx.x/(1.f+__expf(-gv.x)))*m;
  xn.y = (xv.y + mx.y/(1.f+__expf(-gv.y)))*m;
  xn.z = (xv.z + mx.z/(1.f+__expf(-gv.z)))*m;
  xn.w = (xv.w + mx.w/(1.f+__expf(-gv.w)))*m;
  float s = wsum(xn.x+xn.y+xn.z+xn.w);
  float mean = s/256.f;
  float a=xn.x-mean, b2=xn.y-mean, c2=xn.z-mean, d2=xn.w-mean;
  float q = wsum(a*a+b2*b2+c2*c2+d2*d2);
  float rstd = rsqrtf(q/256.f + 1e-5f);
  ((float4*)(x + (size_t)r*256))[lane] = xn;
  float4 gg = ((const float4*)g )[lane];
  float4 bv = ((const float4*)bb)[lane];
  float4 o;
  o.x = a*rstd*gg.x + bv.x;
  o.y = b2*rstd*gg.y + bv.y;
  o.z = c2*rstd*gg.z + bv.z;
  o.w = d2*rstd*gg.w + bv.w;
  ((float4*)(h + (size_t)r*256))[lane] = o;
}

// ---------------- fused: x=(x+f)*mf ; nrm = LN(x) ----------------
__global__ __launch_bounds__(256) void k_addln(
  float* __restrict__ x, const float* __restrict__ f, const int* __restrict__ lens,
  const float* __restrict__ g, const float* __restrict__ bb,
  float* __restrict__ nrm, int maskLN)
{
  int wid = threadIdx.x >> 6, lane = threadIdx.x & 63;
  int r = blockIdx.x*4 + wid;
  int t = r % T_, b = r / T_;
  float m = (t >= T_ - lens[b]) ? 1.f : 0.f;
  float4 xv = ((const float4*)(x + (size_t)r*256))[lane];
  float4 fv = ((const float4*)(f + (size_t)r*256))[lane];
  float4 xn;
  xn.x = (xv.x + fv.x)*m;
  xn.y = (xv.y + fv.y)*m;
  xn.z = (xv.z + fv.z)*m;
  xn.w = (xv.w + fv.w)*m;
  float s = wsum(xn.x+xn.y+xn.z+xn.w);
  float mean = s/256.f;
  float a=xn.x-mean, b2=xn.y-mean, c2=xn.z-mean, d2=xn.w-mean;
  float q = wsum(a*a+b2*b2+c2*c2+d2*d2);
  float rstd = rsqrtf(q/256.f + 1e-5f);
  ((float4*)(x + (size_t)r*256))[lane] = xn;
  float ml = maskLN ? m : 1.f;
  float4 gg = ((const float4*)g )[lane];
  float4 bv = ((const float4*)bb)[lane];
  float4 o;
  o.x = (a*rstd*gg.x + bv.x)*ml;
  o.y = (b2*rstd*gg.y + bv.y)*ml;
  o.z = (c2*rstd*gg.z + bv.z)*ml;
  o.w = (d2*rstd*gg.w + bv.w)*ml;
  ((float4*)(nrm + (size_t)r*256))[lane] = o;
}

// ---------------- pooling ----------------
__global__ __launch_bounds__(256) void k_pool(
  const float* __restrict__ x, const int* __restrict__ lens,
  const float* __restrict__ pg_w, const float* __restrict__ pg_b,
  float* __restrict__ u0)
{
  int b = blockIdx.x;
  int tid = threadIdx.x, wid = tid>>6, lane = tid&63;
  __shared__ float sps[T_];
  __shared__ float spw[T_];
  int len = lens[b]; int tstart = T_ - len;
  const float4* pw4 = (const float4*)pg_w;
  float4 wv = pw4[lane];
  for (int t = wid; t < T_; t += 4){
    const float4* xr = (const float4*)(x + (size_t)(b*T_+t)*D_);
    float4 xv = xr[lane];
    float dot = xv.x*wv.x + xv.y*wv.y + xv.z*wv.z + xv.w*wv.w;
    dot = wsum(dot);
    if (lane==0) sps[t] = (t >= tstart) ? dot + pg_b[0] : -1e9f;
  }
  __syncthreads();
  float mx = -1e30f;
  for (int t=0;t<T_;t++) mx = fmaxf(mx, sps[t]);
  float sum = 0.f;
  for (int t=0;t<T_;t++) sum += __expf(sps[t]-mx);
  float inv = 1.f/sum;
  if (tid < T_) spw[tid] = __expf(sps[tid]-mx)*inv;
  __syncthreads();
  int d = tid;
  float macc=0.f, aacc=0.f;
  for (int t=0;t<T_;t++){
    float v = x[(size_t)(b*T_+t)*D_ + d];
    macc += v;
    aacc += spw[t]*v;
  }
  u0[b*768 + d]       = x[(size_t)(b*T_+T_-1)*D_ + d];
  u0[b*768 + 256 + d] = macc / (float)max(len,1);
  u0[b*768 + 512 + d] = aacc;
}

// ---------------- normalize u rows + emit bf16 ----------------
__global__ __launch_bounds__(64) void k_norm(float* __restrict__ u, unsigned short* __restrict__ ub)
{
  int b = blockIdx.x; int lane = threadIdx.x;
  float4* r = (float4*)(u + b*256);
  float4 v = r[lane];
  float ss = v.x*v.x + v.y*v.y + v.z*v.z + v.w*v.w;
  ss = wsum(ss);
  float sc = 1.f/fmaxf(sqrtf(ss), 1e-12f);
  v.x*=sc; v.y*=sc; v.z*=sc; v.w*=sc;
  r[lane]=v;
  ub[b*256 + lane*4 + 0] = f2bf(v.x);
  ub[b*256 + lane*4 + 1] = f2bf(v.y);
  ub[b*256 + lane*4 + 2] = f2bf(v.z);
  ub[b*256 + lane*4 + 3] = f2bf(v.w);
}

// ---------------- scoring via MFMA: 128 items x 32 users per block ----------------
__global__ __launch_bounds__(256) void k_score_mfma(
  const float* __restrict__ item_emb, const unsigned short* __restrict__ ub,
  const float* __restrict__ item_bias, float* __restrict__ out)
{
  __shared__ unsigned short Als[128][40];
  __shared__ unsigned short Bls[32][264];
  __shared__ float ssA[128][2];
  int tid = threadIdx.x;
  int wave = tid >> 6, lane = tid & 63;
  int frow = lane & 15, kg = lane >> 4;
  int wm = wave * 32;
  int n0 = blockIdx.x * 128;
  for (int i = tid; i < 32*32; i += 256){
    int rr = i >> 5, c = i & 31;
    *(ushort8*)&Bls[rr][c*8] = *(const ushort8*)&ub[rr*256 + c*8];
  }
  int sm = tid >> 1, skh = (tid & 1) * 16;
  float ssreg = 0.f;
  floatx4 acc[2][2];
  #pragma unroll
  for (int i=0;i<2;i++)
    #pragma unroll
    for (int j=0;j<2;j++) acc[i][j] = (floatx4){0.f,0.f,0.f,0.f};

  for (int k0=0; k0<256; k0+=32){
    int gn = n0 + sm;
    float f[16];
    if (gn < NI_){
      const float4* ap = (const float4*)(item_emb + (size_t)(gn+1)*256 + k0 + skh);
      #pragma unroll
      for (int c=0;c<4;c++){ float4 v = ap[c]; f[c*4]=v.x; f[c*4+1]=v.y; f[c*4+2]=v.z; f[c*4+3]=v.w; }
    } else {
      #pragma unroll
      for (int c=0;c<16;c++) f[c]=0.f;
    }
    ushort8 pa, pb;
    #pragma unroll
    for (int c=0;c<8;c++){
      ssreg += f[c]*f[c] + f[8+c]*f[8+c];
      pa[c]=f2bf(f[c]); pb[c]=f2bf(f[8+c]);
    }
    *(ushort8*)&Als[sm][skh]   = pa;
    *(ushort8*)&Als[sm][skh+8] = pb;
    __syncthreads();
    short8 af[2], bf[2];
    #pragma unroll
    for (int i=0;i<2;i++) af[i] = *(const short8*)&Als[wm + 16*i + frow][kg*8];
    #pragma unroll
    for (int j=0;j<2;j++) bf[j] = *(const short8*)&Bls[16*j + frow][k0 + kg*8];
    #pragma unroll
    for (int i=0;i<2;i++)
      #pragma unroll
      for (int j=0;j<2;j++)
        acc[i][j] = __builtin_amdgcn_mfma_f32_16x16x32_bf16(af[i], bf[j], acc[i][j], 0, 0, 0);
    __syncthreads();
  }
  ssA[sm][tid&1] = ssreg;
  __syncthreads();
  #pragma unroll
  for (int i=0;i<2;i++){
    #pragma unroll
    for (int r=0;r<4;r++){
      int ml = wm + 16*i + kg*4 + r;
      int n = n0 + ml;
      if (n < NI_){
        float ss = ssA[ml][0] + ssA[ml][1];
        float sc = 1.f/fmaxf(sqrtf(ss), 1e-12f);
        float bias = item_bias[n+1];
        #pragma unroll
        for (int j=0;j<2;j++){
          int bcol = 16*j + frow;
          out[(size_t)bcol*NI_ + n] = acc[i][j][r]*sc + bias;
        }
      }
    }
  }
}

extern "C" void kernel_launch(void* const* d_in, const int* in_sizes, int n_in,
                              void* d_out, int out_size, void* d_ws, size_t ws_size,
                              hipStream_t stream)
{
  const int* ids  = (const int*)d_in[0];
  const int* ts   = (const int*)d_in[1];
  const int* lens = (const int*)d_in[2];
  const float* item_emb = (const float*)d_in[3];
  const float* pos_emb  = (const float*)d_in[4];
  const float* gap_emb  = (const float*)d_in[5];
  const float* rec_emb  = (const float*)d_in[6];
  const float* tf_w1 = (const float*)d_in[7];
  const float* tf_b1 = (const float*)d_in[8];
  const float* tf_w2 = (const float*)d_in[9];
  const float* tf_b2 = (const float*)d_in[10];
  const float* in_g  = (const float*)d_in[11];
  const float* in_b  = (const float*)d_in[12];
  const float* l_ln1g = (const float*)d_in[13];
  const float* l_ln1b = (const float*)d_in[14];
  const float* l_win  = (const float*)d_in[15];
  const float* l_bin  = (const float*)d_in[16];
  const float* l_wc   = (const float*)d_in[17];
  const float* l_bc   = (const float*)d_in[18];
  const float* l_tw   = (const float*)d_in[19];
  const float* l_tb   = (const float*)d_in[20];
  const float* l_pw   = (const float*)d_in[21];
  const float* l_pb   = (const float*)d_in[22];
  const float* l_wmix = (const float*)d_in[23];
  const float* l_bmix = (const float*)d_in[24];
  const float* l_ln2g = (const float*)d_in[25];
  const float* l_ln2b = (const float*)d_in[26];
  const float* l_wf1  = (const float*)d_in[27];
  const float* l_bf1  = (const float*)d_in[28];
  const float* l_wf2  = (const float*)d_in[29];
  const float* l_bf2  = (const float*)d_in[30];
  const float* fn_g = (const float*)d_in[31];
  const float* fn_b = (const float*)d_in[32];
  const float* pg_w = (const float*)d_in[33];
  const float* pg_b = (const float*)d_in[34];
  const float* uh_w1 = (const float*)d_in[35];
  const float* uh_b1 = (const float*)d_in[36];
  const float* uh_lng = (const float*)d_in[37];
  const float* uh_lnb = (const float*)d_in[38];
  const float* uh_w2 = (const float*)d_in[39];
  const float* uh_b2 = (const float*)d_in[40];
  const float* item_bias = (const float*)d_in[41];
  float* out = (float*)d_out;

  const int MT = B_*T_;
  float* ws   = (float*)d_ws;
  float* xbuf = ws;                               // 1,638,400
  float* tmp  = xbuf + (size_t)MT*D_;             // 1,638,400 (nrm / h)
  float* proj = tmp  + (size_t)MT*D_;             // 4,096,000 (also ffn2 out)
  float* cat  = proj + (size_t)MT*640;            // 4,096,000 (640-wide)
  float* mid  = cat  + (size_t)MT*640;            // 6,553,600 (mixed 256 / ffn1 1024)
  float* u0   = mid  + (size_t)MT*FF_;            // 24,576
  float* u1   = u0 + 32*768;                      // 32,768
  float* u2   = u1 + 32*1024;                     // 8,192
  float* WcombF = u2 + 32*256;                    // 262,144 (8 x 128 x 256)
  float* bmixP  = WcombF + 262144;                // 2,048
  float* Ssum   = bmixP + 2048;                   // 1,081,344 (128 bh x 8 c x 1056)
  unsigned short* WtPerm = (unsigned short*)(Ssum + 1081344);  // 5,505,024 ush
  unsigned short* WtMixT = WtPerm + 5505024;      // 1,572,864 ush
  unsigned short* WtBig  = WtMixT + 1572864;      // 1,310,720 ush
  unsigned short* WtH    = WtBig  + 1310720;      // 1,114,112 ush
  unsigned short* u2b    = WtH    + 1114112;      // 8,192 ush

  // ---- weight prep (one-time per launch) ----
  k_cvtAll<<<8000, 256, 0, stream>>>(l_win, l_wmix, l_wf1, l_wf2, tf_w2, uh_w1, uh_w2,
                                     WtPerm, WtMixT, WtH);
  k_gemm_bf<64><<<dim3(4,1,8), 256, 0, stream>>>(l_wc, WtMixT, nullptr, WcombF,
                                                 128, 256, 256, 256, 768, 256, 0,
                                                 (size_t)128*256, (size_t)196608, (size_t)32768, 0);
  k_asm<<<64, 256, 0, stream>>>(WcombF, WtMixT, WtBig);
  k_bfold<<<8, 256, 0, stream>>>(l_bc, l_bmix, l_wmix, bmixP);

  // ---- embedding + dense time ----
  k_embed<<<MT, 256, 0, stream>>>(ids, ts, lens, item_emb, pos_emb, gap_emb, rec_emb,
                                  tf_w1, tf_b1, xbuf, tmp);
  k_gemm_bf<64><<<dim3(4,50), 256, 0, stream>>>(tmp, WtH, tf_b2, xbuf,
                                                MT, 256, 256, 256, 256, 256, 2, 0,0,0,0);
  k_ln<1><<<MT/4, 256, 0, stream>>>(xbuf, xbuf, in_g, in_b, MT, lens, 1);
  k_ln<1><<<MT/4, 256, 0, stream>>>(xbuf, tmp, l_ln1g, l_ln1b, MT, lens, 0);

  // ---- layers ----
  for (int i=0;i<L_;i++){
    const unsigned short* WL = WtPerm + (size_t)i*688128;
    k_gemm_bf<128><<<dim3(5,50), 256, 0, stream>>>(tmp, WL, l_bin+i*640, proj,
                                                   MT, 640, 256, 256, 256, 640, 0, 0,0,0,0);
    k_attn_sums<<<B_*H_*8, 64, 0, stream>>>(proj, lens, Ssum);
    k_attn_out<<<B_*H_*8, 64, 0, stream>>>(proj, lens, Ssum, cat);
    k_dwconv<<<MT, 256, 0, stream>>>(tmp, l_tw+i*768, l_tb+i*256, l_pw+i*1280, l_pb+i*256, cat);
    k_gemm_bf<64><<<dim3(4,50), 256, 0, stream>>>(cat, WtBig+(size_t)i*163840, bmixP+i*256, mid,
                                                  MT, 256, 640, 640, 640, 256, 0, 0,0,0,0);
    k_postmix_ln<<<MT/4, 256, 0, stream>>>(xbuf, proj, mid, lens, l_ln2g+i*256, l_ln2b+i*256, tmp);
    k_gemm_bf<128><<<dim3(8,50), 256, 0, stream>>>(tmp, WL+163840, l_bf1+i*FF_, mid,
                                                   MT, FF_, 256, 256, 256, FF_, 1, 0,0,0,0);
    k_gemm_bf<64><<<dim3(4,50), 256, 0, stream>>>(mid, WL+425984, l_bf2+i*256, proj,
                                                  MT, 256, 1024, 1024, 1024, 256, 0, 0,0,0,0);
    bool last = (i == L_-1);
    k_addln<<<MT/4, 256, 0, stream>>>(xbuf, proj, lens,
                                      last ? fn_g : l_ln1g+(i+1)*256,
                                      last ? fn_b : l_ln1b+(i+1)*256,
                                      tmp, last ? 1 : 0);
  }

  // ---- pooling + user head (final LN'd x is in tmp) ----
  k_pool<<<B_, 256, 0, stream>>>(tmp, lens, pg_w, pg_b, u0);
  k_gemm_bf<128><<<dim3(8,1), 256, 0, stream>>>(u0, WtH+65536, uh_b1, u1,
                                                32, 1024, 768, 768, 768, 1024, 1, 0,0,0,0);
  k_ln<4><<<8, 256, 0, stream>>>(u1, u1, uh_lng, uh_lnb, 32, lens, 0);
  k_gemm_bf<64><<<dim3(4,1), 256, 0, stream>>>(u1, WtH+851968, uh_b2, u2,
                                               32, 256, 1024, 1024, 1024, 256, 0, 0,0,0,0);
  k_norm<<<B_, 64, 0, stream>>>(u2, u2b);

  // ---- scoring ----
  k_score_mfma<<<(NI_+127)/128, 256, 0, stream>>>(item_emb, u2b, item_bias, out);
}